// Round 11
// baseline (517.761 us; speedup 1.0000x reference)
//
#include <hip/hip_runtime.h>
#include <math.h>

#define NN 20000
#define NE 256000
#define IN_DIM 64
#define HID 128
#define DE 289     // 2*HID + 1 + 32
#define D0 320     // IN_DIM + 2*HID
#define TILE_E 64
#define NB64 313   // ceil(NN/64)
#define NUB 16     // nodes per block (node update)

typedef unsigned short u16;
typedef unsigned int u32;
typedef unsigned long long u64;
typedef __attribute__((ext_vector_type(8))) short short8;
typedef __attribute__((ext_vector_type(4))) float float4v;

// Bpack layout offsets (u16 elements)
#define OFF_WE   0          // 3 x 40960 (K=289 pad 320, N=128) — tiles 0..3 = We rows 0..255
#define OFF_W0   122880     // 40960 (K=320, N=128)
#define OFF_W1   163840     // 16384 (K=128, N=128)
#define OFF_W2   180224     // 16384
#define OFF_WH   196608     // 3 x 32768 (K=256, N=128)
#define OFF_H2I  294912     // 8192 (K=128, N=64)
#define PACK_TOT 303104

static __device__ __forceinline__ u16 f2bf(float f) {
    unsigned int u = __float_as_uint(f);
    u += 0x7fffu + ((u >> 16) & 1u);
    return (u16)(u >> 16);
}
static __device__ __forceinline__ float bf2f(u16 s) {
    return __uint_as_float(((unsigned int)s) << 16);
}
static __device__ __forceinline__ float bflo(u32 u) { return bf2f((u16)(u & 0xffffu)); }
static __device__ __forceinline__ float bfhi(u32 u) { return bf2f((u16)(u >> 16)); }
static __device__ __forceinline__ uint4 pack8(const float* v) {
    uint4 r;
    r.x = (u32)f2bf(v[0]) | ((u32)f2bf(v[1]) << 16);
    r.y = (u32)f2bf(v[2]) | ((u32)f2bf(v[3]) << 16);
    r.z = (u32)f2bf(v[4]) | ((u32)f2bf(v[5]) << 16);
    r.w = (u32)f2bf(v[6]) | ((u32)f2bf(v[7]) << 16);
    return r;
}
static __device__ __forceinline__ float silu(float v) {
    return v * (1.f / (1.f + __expf(-v)));
}

// ================= CSR build =================
__global__ __launch_bounds__(256) void hist_kernel(
    const float* __restrict__ X_t, const int* __restrict__ edges,
    float* __restrict__ x, int* __restrict__ deg)
{
    int gid = blockIdx.x * blockDim.x + threadIdx.x;
    int stride = gridDim.x * blockDim.x;
    for (int i = gid; i < NN * 3; i += stride) x[i] = X_t[i];
    for (int e = gid; e < NE; e += stride)
        atomicAdd(&deg[edges[NE + e]], 1);
}

__global__ __launch_bounds__(256) void scan_kernel(
    const int* __restrict__ deg, int* __restrict__ row_start, int* __restrict__ head)
{
    __shared__ int s[256];
    int tx = threadIdx.x;
    const int per = (NN + 255) / 256;
    int st = tx * per, en = st + per;
    if (st > NN) st = NN;
    if (en > NN) en = NN;
    int sum = 0;
    for (int i = st; i < en; ++i) sum += deg[i];
    s[tx] = sum;
    __syncthreads();
    for (int off = 1; off < 256; off <<= 1) {
        int t = (tx >= off) ? s[tx - off] : 0;
        __syncthreads();
        s[tx] += t;
        __syncthreads();
    }
    int run = (tx == 0) ? 0 : s[tx - 1];
    for (int i = st; i < en; ++i) {
        row_start[i] = run; head[i] = run; run += deg[i];
    }
    if (tx == 255) row_start[NN] = run;
}

// permute edges into dst-sorted order
__global__ __launch_bounds__(256) void scatter_kernel(
    const int* __restrict__ edges, const int* __restrict__ etype,
    int* __restrict__ head,
    int* __restrict__ src_s, int* __restrict__ dst_s, int* __restrict__ et_s)
{
    int gid = blockIdx.x * blockDim.x + threadIdx.x;
    int stride = gridDim.x * blockDim.x;
    for (int e = gid; e < NE; e += stride) {
        int d = edges[NE + e];
        int p = atomicAdd(&head[d], 1);
        src_s[p] = edges[e];
        dst_s[p] = d;
        et_s[p] = etype[e];
    }
}

// ================= weight frag-order packing =================
__global__ __launch_bounds__(256) void pack_all_kernel(
    const float* __restrict__ We, const float* __restrict__ W0,
    const float* __restrict__ W1, const float* __restrict__ W2,
    const float* __restrict__ Wh, const float* __restrict__ h2i,
    u16* __restrict__ Bp)
{
    int idx = blockIdx.x * 256 + threadIdx.x;
    if (idx >= PACK_TOT) return;
    const float* src; int N = 128, Ksrc; int r;
    if (idx < OFF_W0) {
        int layer = idx / 40960; r = idx - layer * 40960;
        src = We + (size_t)layer * DE * HID; Ksrc = DE;
    } else if (idx < OFF_W1) { r = idx - OFF_W0; src = W0; Ksrc = 320; }
    else if (idx < OFF_W2)   { r = idx - OFF_W1; src = W1; Ksrc = 128; }
    else if (idx < OFF_WH)   { r = idx - OFF_W2; src = W2; Ksrc = 128; }
    else if (idx < OFF_H2I) {
        int t = idx - OFF_WH; int layer = t / 32768; r = t - layer * 32768;
        src = Wh + (size_t)layer * 256 * HID; Ksrc = 256;
    } else { r = idx - OFF_H2I; src = h2i; Ksrc = 128; N = 64; }
    int ntc = N / 16;
    int j = r & 7, lane = (r >> 3) & 63;
    int rem = r >> 9;
    int nt = rem % ntc, ks = rem / ntc;
    int k = ks * 32 + ((lane >> 4) << 3) + j;
    int c = nt * 16 + (lane & 15);
    Bp[idx] = f2bf((k < Ksrc) ? src[(size_t)k * N + c] : 0.f);
}

// ================= edge tail precompute (f32) =================
__global__ __launch_bounds__(256) void precomp_tv_kernel(
    const float* __restrict__ edge_table, const float* __restrict__ We,
    const float* __restrict__ be, float* __restrict__ tv, float* __restrict__ wed2)
{
    int idx = blockIdx.x * 256 + threadIdx.x;
    if (idx < 768) {
        int f = idx & 127, t = (idx >> 7) & 1, l = idx >> 8;
        float acc = be[l * 128 + f];
        const float* W = We + (size_t)l * DE * HID;
        #pragma unroll
        for (int k = 0; k < 32; ++k)
            acc += edge_table[t * 32 + k] * W[(size_t)(257 + k) * HID + f];
        tv[l * 256 + t * 128 + f] = acc;
    } else if (idx < 1152) {
        int r = idx - 768;
        int f = r & 127, l = r >> 7;
        wed2[l * 128 + f] = We[(size_t)l * DE * HID + (size_t)256 * HID + f];
    }
}

// ================= node MLP: MFMA, 64 nodes/block =================
__global__ __launch_bounds__(256) void node_mlp_mfma_kernel(
    const float* __restrict__ H_t, const float* __restrict__ cond,
    const float* __restrict__ t_in,
    const u16* __restrict__ W0p, const float* __restrict__ b0,
    const u16* __restrict__ W1p, const float* __restrict__ b1,
    const u16* __restrict__ W2p, const float* __restrict__ b2,
    float* __restrict__ h, u16* __restrict__ h_bf)
{
    __shared__ u16 s_A[64 * 64];
    __shared__ u16 s_B[64 * 128];
    __shared__ u16 s_h[64 * 128];
    __shared__ float s_t[64];

    int tx = threadIdx.x;
    int n0 = blockIdx.x * 64;
    int l = tx & 63, w = tx >> 6;
    int mt_base = (w & 1) * 2, nt_base = (w >> 1) * 4;
    const float cfr = -logf(10000.f) / 63.f;

    if (tx < 64) s_t[tx] = (n0 + tx < NN) ? t_in[n0 + tx] : 0.f;

    float4v acc[2][4];
    #pragma unroll
    for (int mi = 0; mi < 2; ++mi)
        #pragma unroll
        for (int ni = 0; ni < 4; ++ni) acc[mi][ni] = (float4v){0.f,0.f,0.f,0.f};

    for (int t = 0; t < 5; ++t) {
        __syncthreads();
        #pragma unroll
        for (int it = 0; it < 2; ++it) {
            int flat = it * 256 + tx;
            int n = flat >> 3, sl = flat & 7;
            int c = sl ^ (n & 7);
            int k0 = t * 64 + c * 8;
            float tv8[8];
            int gn = n0 + n;
            if (gn < NN) {
                if (k0 < 192) {
                    const float* src = (k0 < 64) ? &H_t[(size_t)gn * IN_DIM + k0]
                                                 : &cond[(size_t)gn * HID + (k0 - 64)];
                    float4 a = *(const float4*)src;
                    float4 b = *(const float4*)(src + 4);
                    tv8[0]=a.x; tv8[1]=a.y; tv8[2]=a.z; tv8[3]=a.w;
                    tv8[4]=b.x; tv8[5]=b.y; tv8[6]=b.z; tv8[7]=b.w;
                } else {
                    float tv = s_t[n];
                    int jj = (k0 - 192) & 63;
                    bool is_sin = (k0 < 256);
                    #pragma unroll
                    for (int jx = 0; jx < 8; ++jx) {
                        float ang = tv * __expf(cfr * (float)(jj + jx));
                        tv8[jx] = is_sin ? __sinf(ang) : __cosf(ang);
                    }
                }
            } else {
                #pragma unroll
                for (int jx = 0; jx < 8; ++jx) tv8[jx] = 0.f;
            }
            *(uint4*)&s_A[n * 64 + sl * 8] = pack8(tv8);
        }
        #pragma unroll
        for (int it = 0; it < 4; ++it) {
            int flat = it * 256 + tx;
            ((uint4*)s_B)[flat] = ((const uint4*)(W0p + (size_t)t * 8192))[flat];
        }
        __syncthreads();
        #pragma unroll
        for (int s = 0; s < 2; ++s) {
            short8 af[2], bfv[4];
            #pragma unroll
            for (int mi = 0; mi < 2; ++mi) {
                int m = (mt_base + mi) * 16 + (l & 15);
                int c = s * 4 + (l >> 4);
                int slot = c ^ (l & 7);
                af[mi] = *(const short8*)(s_A + m * 64 + slot * 8);
            }
            #pragma unroll
            for (int ni = 0; ni < 4; ++ni)
                bfv[ni] = *(const short8*)(s_B + ((s * 8 + nt_base + ni) * 64 + l) * 8);
            #pragma unroll
            for (int mi = 0; mi < 2; ++mi)
                #pragma unroll
                for (int ni = 0; ni < 4; ++ni)
                    acc[mi][ni] = __builtin_amdgcn_mfma_f32_16x16x32_bf16(
                        af[mi], bfv[ni], acc[mi][ni], 0, 0, 0);
        }
    }
    #pragma unroll
    for (int mi = 0; mi < 2; ++mi) {
        #pragma unroll
        for (int ni = 0; ni < 4; ++ni) {
            int f = (nt_base + ni) * 16 + (l & 15);
            float bv = b0[f];
            #pragma unroll
            for (int r = 0; r < 4; ++r) {
                int m = (mt_base + mi) * 16 + (l >> 4) * 4 + r;
                float v = fmaxf(acc[mi][ni][r] + bv, 0.f);
                int slot = (f >> 3) ^ (m & 7);
                s_h[m * 128 + slot * 8 + (f & 7)] = f2bf(v);
            }
            acc[mi][ni] = (float4v){0.f,0.f,0.f,0.f};
        }
    }
    for (int t = 0; t < 2; ++t) {
        __syncthreads();
        #pragma unroll
        for (int it = 0; it < 4; ++it) {
            int flat = it * 256 + tx;
            ((uint4*)s_B)[flat] = ((const uint4*)(W1p + (size_t)t * 8192))[flat];
        }
        __syncthreads();
        #pragma unroll
        for (int s = 0; s < 2; ++s) {
            short8 af[2], bfv[4];
            #pragma unroll
            for (int mi = 0; mi < 2; ++mi) {
                int m = (mt_base + mi) * 16 + (l & 15);
                int c = t * 8 + s * 4 + (l >> 4);
                int slot = c ^ (l & 7);
                af[mi] = *(const short8*)(s_h + m * 128 + slot * 8);
            }
            #pragma unroll
            for (int ni = 0; ni < 4; ++ni)
                bfv[ni] = *(const short8*)(s_B + ((s * 8 + nt_base + ni) * 64 + l) * 8);
            #pragma unroll
            for (int mi = 0; mi < 2; ++mi)
                #pragma unroll
                for (int ni = 0; ni < 4; ++ni)
                    acc[mi][ni] = __builtin_amdgcn_mfma_f32_16x16x32_bf16(
                        af[mi], bfv[ni], acc[mi][ni], 0, 0, 0);
        }
    }
    __syncthreads();
    #pragma unroll
    for (int mi = 0; mi < 2; ++mi) {
        #pragma unroll
        for (int ni = 0; ni < 4; ++ni) {
            int f = (nt_base + ni) * 16 + (l & 15);
            float bv = b1[f];
            #pragma unroll
            for (int r = 0; r < 4; ++r) {
                int m = (mt_base + mi) * 16 + (l >> 4) * 4 + r;
                float v = fmaxf(acc[mi][ni][r] + bv, 0.f);
                int slot = (f >> 3) ^ (m & 7);
                s_h[m * 128 + slot * 8 + (f & 7)] = f2bf(v);
            }
            acc[mi][ni] = (float4v){0.f,0.f,0.f,0.f};
        }
    }
    for (int t = 0; t < 2; ++t) {
        __syncthreads();
        #pragma unroll
        for (int it = 0; it < 4; ++it) {
            int flat = it * 256 + tx;
            ((uint4*)s_B)[flat] = ((const uint4*)(W2p + (size_t)t * 8192))[flat];
        }
        __syncthreads();
        #pragma unroll
        for (int s = 0; s < 2; ++s) {
            short8 af[2], bfv[4];
            #pragma unroll
            for (int mi = 0; mi < 2; ++mi) {
                int m = (mt_base + mi) * 16 + (l & 15);
                int c = t * 8 + s * 4 + (l >> 4);
                int slot = c ^ (l & 7);
                af[mi] = *(const short8*)(s_h + m * 128 + slot * 8);
            }
            #pragma unroll
            for (int ni = 0; ni < 4; ++ni)
                bfv[ni] = *(const short8*)(s_B + ((s * 8 + nt_base + ni) * 64 + l) * 8);
            #pragma unroll
            for (int mi = 0; mi < 2; ++mi)
                #pragma unroll
                for (int ni = 0; ni < 4; ++ni)
                    acc[mi][ni] = __builtin_amdgcn_mfma_f32_16x16x32_bf16(
                        af[mi], bfv[ni], acc[mi][ni], 0, 0, 0);
        }
    }
    #pragma unroll
    for (int mi = 0; mi < 2; ++mi) {
        #pragma unroll
        for (int ni = 0; ni < 4; ++ni) {
            int f = (nt_base + ni) * 16 + (l & 15);
            float bv = b2[f];
            #pragma unroll
            for (int r = 0; r < 4; ++r) {
                int m = (mt_base + mi) * 16 + (l >> 4) * 4 + r;
                int gn = n0 + m;
                if (gn < NN) {
                    float v = acc[mi][ni][r] + bv;
                    h[(size_t)gn * HID + f] = v;
                    h_bf[(size_t)gn * HID + f] = f2bf(v);
                }
            }
        }
    }
}

// ================= cvec: C[n][0:128]=h@We_src, C[n][128:256]=h@We_dst (bf16 out) =================
__global__ __launch_bounds__(256) void cvec_kernel(
    const u16* __restrict__ h_bf, const u16* __restrict__ WEp,
    u16* __restrict__ Cbf)
{
    __shared__ u16 s_A[64 * 64];
    __shared__ u16 s_B[64 * 128];

    int tx = threadIdx.x;
    int n0 = blockIdx.x * 64;
    int l = tx & 63, w = tx >> 6;
    int mt_base = (w & 1) * 2, nt_base = (w >> 1) * 4;

    float4v acc[2][2][4];  // [side][mi][ni]
    #pragma unroll
    for (int sd = 0; sd < 2; ++sd)
        #pragma unroll
        for (int mi = 0; mi < 2; ++mi)
            #pragma unroll
            for (int ni = 0; ni < 4; ++ni)
                acc[sd][mi][ni] = (float4v){0.f,0.f,0.f,0.f};

    for (int t = 0; t < 4; ++t) {
        __syncthreads();
        #pragma unroll
        for (int it = 0; it < 2; ++it) {
            int flat = it * 256 + tx;
            int n = flat >> 3, sl = flat & 7;
            int c = sl ^ (n & 7);
            int gn = n0 + n;
            uint4 v = make_uint4(0,0,0,0);
            if (gn < NN) v = *(const uint4*)(h_bf + (size_t)gn * 128 + (t & 1) * 64 + c * 8);
            *(uint4*)&s_A[n * 64 + sl * 8] = v;
        }
        #pragma unroll
        for (int it = 0; it < 4; ++it) {
            int flat = it * 256 + tx;
            ((uint4*)s_B)[flat] = ((const uint4*)(WEp + (size_t)t * 8192))[flat];
        }
        __syncthreads();
        int sd = t >> 1;
        #pragma unroll
        for (int s = 0; s < 2; ++s) {
            short8 af[2], bfv[4];
            #pragma unroll
            for (int mi = 0; mi < 2; ++mi) {
                int m = (mt_base + mi) * 16 + (l & 15);
                int c = s * 4 + (l >> 4);
                int slot = c ^ (l & 7);
                af[mi] = *(const short8*)(s_A + m * 64 + slot * 8);
            }
            #pragma unroll
            for (int ni = 0; ni < 4; ++ni)
                bfv[ni] = *(const short8*)(s_B + ((s * 8 + nt_base + ni) * 64 + l) * 8);
            #pragma unroll
            for (int mi = 0; mi < 2; ++mi)
                #pragma unroll
                for (int ni = 0; ni < 4; ++ni)
                    acc[sd][mi][ni] = __builtin_amdgcn_mfma_f32_16x16x32_bf16(
                        af[mi], bfv[ni], acc[sd][mi][ni], 0, 0, 0);
        }
    }
    #pragma unroll
    for (int sd = 0; sd < 2; ++sd) {
        #pragma unroll
        for (int mi = 0; mi < 2; ++mi) {
            #pragma unroll
            for (int ni = 0; ni < 4; ++ni) {
                int f = sd * 128 + (nt_base + ni) * 16 + (l & 15);
                #pragma unroll
                for (int r = 0; r < 4; ++r) {
                    int m = (mt_base + mi) * 16 + (l >> 4) * 4 + r;
                    int gn = n0 + m;
                    if (gn < NN)
                        Cbf[(size_t)gn * 256 + f] = f2bf(acc[sd][mi][ni][r]);
                }
            }
        }
    }
}

// ================= edge pass: gather + add + silu + msg/wdiff (no MFMA) =================
__global__ __launch_bounds__(256) void edge_pass_kernel(
    const u16* __restrict__ Cbf, const float* __restrict__ x,
    const int* __restrict__ src_s, const int* __restrict__ dst_s,
    const int* __restrict__ et_s,
    const float* __restrict__ tv_l, const float* __restrict__ wed2_l,
    const float* __restrict__ Wx_l, const float* __restrict__ bx_l,
    u16* __restrict__ msg, float* __restrict__ wdiff)
{
    __shared__ int s_src[64], s_dst[64], s_et[64];
    __shared__ float s_diff[64][3], s_d2[64];

    int tx = threadIdx.x;
    int e0 = blockIdx.x * 64;

    if (tx < 64) {
        int s = src_s[e0 + tx], d = dst_s[e0 + tx];
        s_src[tx] = s; s_dst[tx] = d; s_et[tx] = et_s[e0 + tx];
        float dx = x[s*3+0]-x[d*3+0], dy = x[s*3+1]-x[d*3+1], dz = x[s*3+2]-x[d*3+2];
        s_diff[tx][0] = dx; s_diff[tx][1] = dy; s_diff[tx][2] = dz;
        s_d2[tx] = dx*dx + dy*dy + dz*dz;
    }
    __syncthreads();

    int e = tx >> 2, p = tx & 3;      // thread covers 32 feats of one edge
    int gs = s_src[e], gd = s_dst[e], et = s_et[e];
    float d2 = s_d2[e];
    const u16* cs = Cbf + (size_t)gs * 256 + p * 32;
    const u16* cd = Cbf + (size_t)gd * 256 + 128 + p * 32;
    const float* tvp = tv_l + et * 128 + p * 32;
    const float* wdp = wed2_l + p * 32;
    const float* wxp = Wx_l + p * 32;

    float wsum = 0.f;
    #pragma unroll
    for (int q = 0; q < 4; ++q) {
        uint4 a = *(const uint4*)(cs + q * 8);
        uint4 b = *(const uint4*)(cd + q * 8);
        float4 t0 = *(const float4*)(tvp + q * 8);
        float4 t1 = *(const float4*)(tvp + q * 8 + 4);
        float4 w0 = *(const float4*)(wdp + q * 8);
        float4 w1 = *(const float4*)(wdp + q * 8 + 4);
        float4 x0 = *(const float4*)(wxp + q * 8);
        float4 x1 = *(const float4*)(wxp + q * 8 + 4);
        float av[8] = {bflo(a.x), bfhi(a.x), bflo(a.y), bfhi(a.y),
                       bflo(a.z), bfhi(a.z), bflo(a.w), bfhi(a.w)};
        float bv[8] = {bflo(b.x), bfhi(b.x), bflo(b.y), bfhi(b.y),
                       bflo(b.z), bfhi(b.z), bflo(b.w), bfhi(b.w)};
        float tt[8] = {t0.x, t0.y, t0.z, t0.w, t1.x, t1.y, t1.z, t1.w};
        float wd[8] = {w0.x, w0.y, w0.z, w0.w, w1.x, w1.y, w1.z, w1.w};
        float wx[8] = {x0.x, x0.y, x0.z, x0.w, x1.x, x1.y, x1.z, x1.w};
        float mv[8];
        #pragma unroll
        for (int j = 0; j < 8; ++j) {
            float v = av[j] + bv[j] + tt[j] + d2 * wd[j];
            float m = silu(v);
            mv[j] = m;
            wsum += m * wx[j];
        }
        *(uint4*)(msg + (size_t)(e0 + e) * 128 + p * 32 + q * 8) = pack8(mv);
    }
    wsum += __shfl_xor(wsum, 1);
    wsum += __shfl_xor(wsum, 2);
    if (p < 3)
        wdiff[(size_t)(e0 + e) * 3 + p] = s_diff[e][p] * (wsum + bx_l[0]);
}

// ================= node update: CSR agg + MFMA Wh GEMM, 16 nodes/block =================
__global__ __launch_bounds__(256) void node_update_mfma_kernel(
    float* __restrict__ h, u16* __restrict__ h_bf, float* __restrict__ x,
    const u16* __restrict__ msg, const float* __restrict__ wdiff,
    const int* __restrict__ row_start,
    const u16* __restrict__ Whp_l, const float* __restrict__ bh_l)
{
    __shared__ u16 s_A[NUB * 256];   // 8 KB
    __shared__ u16 s_B[64 * 128];    // 16 KB
    __shared__ int s_rs[NUB + 1];

    int tx = threadIdx.x;
    int n0 = blockIdx.x * NUB;
    int l = tx & 63, w = tx >> 6;
    int nt_base = w * 2;

    if (tx < NUB + 1) s_rs[tx] = row_start[n0 + tx];
    {
        int n = tx >> 4, c = tx & 15;
        int slot = c ^ (n & 7);
        uint4 v = *(const uint4*)(h_bf + (size_t)(n0 + n) * 128 + c * 8);
        *(uint4*)&s_A[n * 256 + slot * 8] = v;
    }
    __syncthreads();
    {
        int i = tx >> 4, p = tx & 15;
        int rs = s_rs[i], re = s_rs[i + 1];
        float ag[8];
        #pragma unroll
        for (int q = 0; q < 8; ++q) ag[q] = 0.f;
        for (int j = rs; j < re; ++j) {
            uint4 v = *(const uint4*)(msg + (size_t)j * 128 + p * 8);
            ag[0] += bflo(v.x); ag[1] += bfhi(v.x);
            ag[2] += bflo(v.y); ag[3] += bfhi(v.y);
            ag[4] += bflo(v.z); ag[5] += bfhi(v.z);
            ag[6] += bflo(v.w); ag[7] += bfhi(v.w);
        }
        int c2 = 16 + p;
        int slot = c2 ^ (i & 7);
        *(uint4*)&s_A[i * 256 + slot * 8] = pack8(ag);
    }
    if (tx < NUB * 3) {
        int i = tx / 3, c = tx % 3;
        int gn = n0 + i;
        int rs = s_rs[i], re = s_rs[i + 1];
        float sxx = 0.f;
        for (int j = rs; j < re; ++j) sxx += wdiff[j * 3 + c];
        x[gn * 3 + c] += sxx / ((float)(re - rs) + 1.f);
    }

    float4v acc[2];
    #pragma unroll
    for (int ni = 0; ni < 2; ++ni) acc[ni] = (float4v){0.f,0.f,0.f,0.f};

    for (int t = 0; t < 4; ++t) {
        __syncthreads();
        #pragma unroll
        for (int it = 0; it < 4; ++it) {
            int flat = it * 256 + tx;
            ((uint4*)s_B)[flat] = ((const uint4*)(Whp_l + (size_t)t * 8192))[flat];
        }
        __syncthreads();
        #pragma unroll
        for (int s = 0; s < 2; ++s) {
            short8 af, bfv[2];
            {
                int m = l & 15;
                int c = t * 8 + s * 4 + (l >> 4);
                int slot = c ^ (l & 7);
                af = *(const short8*)(s_A + m * 256 + slot * 8);
            }
            #pragma unroll
            for (int ni = 0; ni < 2; ++ni)
                bfv[ni] = *(const short8*)(s_B + ((s * 8 + nt_base + ni) * 64 + l) * 8);
            #pragma unroll
            for (int ni = 0; ni < 2; ++ni)
                acc[ni] = __builtin_amdgcn_mfma_f32_16x16x32_bf16(
                    af, bfv[ni], acc[ni], 0, 0, 0);
        }
    }
    #pragma unroll
    for (int ni = 0; ni < 2; ++ni) {
        int f = (nt_base + ni) * 16 + (l & 15);
        float bv = bh_l[f];
        #pragma unroll
        for (int r = 0; r < 4; ++r) {
            int m = (l >> 4) * 4 + r;
            int gn = n0 + m;
            float v = acc[ni][r] + bv;
            float hn = h[(size_t)gn * HID + f] + silu(v);
            h[(size_t)gn * HID + f] = hn;
            h_bf[(size_t)gn * HID + f] = f2bf(hn);
        }
    }
}

// ================= final: MFMA h2i, 64 nodes/block =================
__global__ __launch_bounds__(256) void final_mfma_kernel(
    const u16* __restrict__ h_bf, const float* __restrict__ x,
    const int* __restrict__ gmask,
    const u16* __restrict__ h2ip, const float* __restrict__ b,
    float* __restrict__ out)
{
    __shared__ u16 s_A[64 * 128];
    __shared__ u16 s_B[4096];

    int tx = threadIdx.x;
    int n0 = blockIdx.x * 64;
    int l = tx & 63, w = tx >> 6;
    int mt_base = (w & 1) * 2, nt_base = (w >> 1) * 2;

    #pragma unroll
    for (int it = 0; it < 4; ++it) {
        int flat = it * 256 + tx;
        int n = flat >> 4, c = flat & 15;
        int slot = c ^ (n & 7);
        int gn = n0 + n;
        uint4 v = make_uint4(0,0,0,0);
        if (gn < NN) v = *(const uint4*)(h_bf + (size_t)gn * 128 + c * 8);
        *(uint4*)&s_A[n * 128 + slot * 8] = v;
    }

    float4v acc[2][2];
    #pragma unroll
    for (int mi = 0; mi < 2; ++mi)
        #pragma unroll
        for (int ni = 0; ni < 2; ++ni) acc[mi][ni] = (float4v){0.f,0.f,0.f,0.f};

    for (int t = 0; t < 2; ++t) {
        __syncthreads();
        #pragma unroll
        for (int it = 0; it < 2; ++it) {
            int flat = it * 256 + tx;
            ((uint4*)s_B)[flat] = ((const uint4*)(h2ip + (size_t)t * 4096))[flat];
        }
        __syncthreads();
        #pragma unroll
        for (int s = 0; s < 2; ++s) {
            short8 af[2], bfv[2];
            #pragma unroll
            for (int mi = 0; mi < 2; ++mi) {
                int m = (mt_base + mi) * 16 + (l & 15);
                int c = t * 8 + s * 4 + (l >> 4);
                int slot = c ^ (l & 7);
                af[mi] = *(const short8*)(s_A + m * 128 + slot * 8);
            }
            #pragma unroll
            for (int ni = 0; ni < 2; ++ni)
                bfv[ni] = *(const short8*)(s_B + ((s * 4 + nt_base + ni) * 64 + l) * 8);
            #pragma unroll
            for (int mi = 0; mi < 2; ++mi)
                #pragma unroll
                for (int ni = 0; ni < 2; ++ni)
                    acc[mi][ni] = __builtin_amdgcn_mfma_f32_16x16x32_bf16(
                        af[mi], bfv[ni], acc[mi][ni], 0, 0, 0);
        }
    }
    #pragma unroll
    for (int mi = 0; mi < 2; ++mi) {
        #pragma unroll
        for (int ni = 0; ni < 2; ++ni) {
            int f = (nt_base + ni) * 16 + (l & 15);
            float bv = b[f];
            #pragma unroll
            for (int r = 0; r < 4; ++r) {
                int m = (mt_base + mi) * 16 + (l >> 4) * 4 + r;
                int gn = n0 + m;
                if (gn < NN)
                    out[(size_t)gn * IN_DIM + f] = gmask[gn] ? (acc[mi][ni][r] + bv) : 0.f;
            }
        }
    }
    if (tx < 192) {
        int i = tx / 3, c = tx % 3;
        int gn = n0 + i;
        if (gn < NN)
            out[(size_t)NN * IN_DIM + gn * 3 + c] = gmask[gn] ? x[gn * 3 + c] : 0.f;
    }
}

// ================= fallback path (atomic, scalar; used only if ws too small) =================
__global__ __launch_bounds__(256) void init_fb_kernel(
    const float* __restrict__ X_t, const int* __restrict__ edges,
    float* __restrict__ x, float* __restrict__ cnt)
{
    int gid = blockIdx.x * blockDim.x + threadIdx.x;
    int stride = gridDim.x * blockDim.x;
    for (int i = gid; i < NN * 3; i += stride) x[i] = X_t[i];
    for (int e = gid; e < NE; e += stride)
        atomicAdd(&cnt[edges[NE + e]], 1.0f);
}

__global__ __launch_bounds__(128) void node_mlp_kernel(
    const float* __restrict__ H_t, const float* __restrict__ cond,
    const float* __restrict__ t_in,
    const float* __restrict__ W0, const float* __restrict__ b0,
    const float* __restrict__ W1, const float* __restrict__ b1,
    const float* __restrict__ W2, const float* __restrict__ b2,
    float* __restrict__ h)
{
    __shared__ float s_feat[D0][20];
    __shared__ float s_h0[HID][20];
    __shared__ float s_h1[HID][20];
    int n0 = blockIdx.x * 16;
    int tx = threadIdx.x;

    for (int idx = tx; idx < 16 * IN_DIM; idx += 128) {
        int i = idx >> 6, k = idx & 63;
        s_feat[k][i] = H_t[(n0 + i) * IN_DIM + k];
    }
    for (int idx = tx; idx < 16 * HID; idx += 128) {
        int i = idx >> 7, k = idx & 127;
        s_feat[IN_DIM + k][i] = cond[(n0 + i) * HID + k];
    }
    const float cfr = -logf(10000.f) / 63.f;
    for (int idx = tx; idx < 16 * HID; idx += 128) {
        int i = idx >> 7, k = idx & 127;
        float tv = t_in[n0 + i];
        int jj = k & 63;
        float ang = tv * __expf(cfr * (float)jj);
        s_feat[IN_DIM + HID + k][i] = (k < 64) ? __sinf(ang) : __cosf(ang);
    }
    __syncthreads();

    float acc[16];
    {
        float bv = b0[tx];
        #pragma unroll
        for (int i = 0; i < 16; ++i) acc[i] = bv;
        for (int k = 0; k < D0; ++k) {
            float w = W0[k * HID + tx];
            float4 f0 = *(const float4*)&s_feat[k][0];
            float4 f1 = *(const float4*)&s_feat[k][4];
            float4 f2 = *(const float4*)&s_feat[k][8];
            float4 f3 = *(const float4*)&s_feat[k][12];
            acc[0] += f0.x*w; acc[1] += f0.y*w; acc[2] += f0.z*w; acc[3] += f0.w*w;
            acc[4] += f1.x*w; acc[5] += f1.y*w; acc[6] += f1.z*w; acc[7] += f1.w*w;
            acc[8] += f2.x*w; acc[9] += f2.y*w; acc[10]+= f2.z*w; acc[11]+= f2.w*w;
            acc[12]+= f3.x*w; acc[13]+= f3.y*w; acc[14]+= f3.z*w; acc[15]+= f3.w*w;
        }
        #pragma unroll
        for (int i = 0; i < 16; ++i) s_h0[tx][i] = fmaxf(acc[i], 0.f);
    }
    __syncthreads();
    {
        float bv = b1[tx];
        #pragma unroll
        for (int i = 0; i < 16; ++i) acc[i] = bv;
        for (int k = 0; k < HID; ++k) {
            float w = W1[k * HID + tx];
            float4 f0 = *(const float4*)&s_h0[k][0];
            float4 f1 = *(const float4*)&s_h0[k][4];
            float4 f2 = *(const float4*)&s_h0[k][8];
            float4 f3 = *(const float4*)&s_h0[k][12];
            acc[0] += f0.x*w; acc[1] += f0.y*w; acc[2] += f0.z*w; acc[3] += f0.w*w;
            acc[4] += f1.x*w; acc[5] += f1.y*w; acc[6] += f1.z*w; acc[7] += f1.w*w;
            acc[8] += f2.x*w; acc[9] += f2.y*w; acc[10]+= f2.z*w; acc[11]+= f2.w*w;
            acc[12]+= f3.x*w; acc[13]+= f3.y*w; acc[14]+= f3.z*w; acc[15]+= f3.w*w;
        }
        #pragma unroll
        for (int i = 0; i < 16; ++i) s_h1[tx][i] = fmaxf(acc[i], 0.f);
    }
    __syncthreads();
    {
        float bv = b2[tx];
        #pragma unroll
        for (int i = 0; i < 16; ++i) acc[i] = bv;
        for (int k = 0; k < HID; ++k) {
            float w = W2[k * HID + tx];
            float4 f0 = *(const float4*)&s_h1[k][0];
            float4 f1 = *(const float4*)&s_h1[k][4];
            float4 f2 = *(const float4*)&s_h1[k][8];
            float4 f3 = *(const float4*)&s_h1[k][12];
            acc[0] += f0.x*w; acc[1] += f0.y*w; acc[2] += f0.z*w; acc[3] += f0.w*w;
            acc[4] += f1.x*w; acc[5] += f1.y*w; acc[6] += f1.z*w; acc[7] += f1.w*w;
            acc[8] += f2.x*w; acc[9] += f2.y*w; acc[10]+= f2.z*w; acc[11]+= f2.w*w;
            acc[12]+= f3.x*w; acc[13]+= f3.y*w; acc[14]+= f3.z*w; acc[15]+= f3.w*w;
        }
        #pragma unroll
        for (int i = 0; i < 16; ++i) h[(n0 + i) * HID + tx] = acc[i];
    }
}

__global__ __launch_bounds__(256) void edge_gemm_fb_kernel(
    const float* __restrict__ h, const float* __restrict__ x,
    const int* __restrict__ edges, const int* __restrict__ etype,
    const float* __restrict__ edge_table,
    const float* __restrict__ We_l, const float* __restrict__ be_l,
    const float* __restrict__ Wx_l, const float* __restrict__ bx_l,
    float* __restrict__ agg_m, float* __restrict__ agg_x)
{
    __shared__ int s_src[TILE_E], s_dst[TILE_E];
    __shared__ float s_diff[TILE_E][3];
    __shared__ float s_tail[TILE_E][36];
    __shared__ float s_Af[TILE_E][36];
    __shared__ float s_Bf[33][HID];
    __shared__ float s_wx[HID];

    int e0 = blockIdx.x * TILE_E;
    int tx = threadIdx.x;
    int tf = tx & 15;
    int te = tx >> 4;

    if (tx < TILE_E) {
        int s = edges[e0 + tx];
        int d = edges[NE + e0 + tx];
        s_src[tx] = s; s_dst[tx] = d;
        float dx = x[s * 3 + 0] - x[d * 3 + 0];
        float dy = x[s * 3 + 1] - x[d * 3 + 1];
        float dz = x[s * 3 + 2] - x[d * 3 + 2];
        s_diff[tx][0] = dx; s_diff[tx][1] = dy; s_diff[tx][2] = dz;
        s_tail[tx][0] = dx * dx + dy * dy + dz * dz;
        int et = etype[e0 + tx];
        #pragma unroll
        for (int j = 0; j < 32; ++j) s_tail[tx][1 + j] = edge_table[et * 32 + j];
    }
    if (tx < HID) s_wx[tx] = Wx_l[tx];
    __syncthreads();

    float acc[4][8];
    #pragma unroll
    for (int i = 0; i < 4; ++i)
        #pragma unroll
        for (int j = 0; j < 8; ++j) acc[i][j] = 0.f;

    for (int t = 0; t < 9; ++t) {
        int k0 = t * 32;
        int klen = (t == 8) ? 33 : 32;
        __syncthreads();
        if (t < 8) {
            const bool use_src = (t < 4);
            int kbase = (t & 3) * 32;
            for (int q4 = tx; q4 < TILE_E * 8; q4 += 256) {
                int e = q4 >> 3, q = q4 & 7;
                int row = use_src ? s_src[e] : s_dst[e];
                float4 v = *(const float4*)&h[row * HID + kbase + q * 4];
                *(float4*)&s_Af[e][q * 4] = v;
            }
        }
        for (int q4 = tx; q4 < klen * 32; q4 += 256) {
            int kk = q4 >> 5, c4 = q4 & 31;
            float4 v = *(const float4*)&We_l[(k0 + kk) * HID + c4 * 4];
            *(float4*)&s_Bf[kk][c4 * 4] = v;
        }
        __syncthreads();
        const float (*Asrc)[36] = (t == 8) ? (const float (*)[36])s_tail
                                           : (const float (*)[36])s_Af;
        for (int kk = 0; kk < klen; ++kk) {
            float a0 = Asrc[te * 4 + 0][kk];
            float a1 = Asrc[te * 4 + 1][kk];
            float a2 = Asrc[te * 4 + 2][kk];
            float a3 = Asrc[te * 4 + 3][kk];
            float4 bv0 = *(const float4*)&s_Bf[kk][tf * 8];
            float4 bv1 = *(const float4*)&s_Bf[kk][tf * 8 + 4];
            float b[8] = {bv0.x, bv0.y, bv0.z, bv0.w, bv1.x, bv1.y, bv1.z, bv1.w};
            #pragma unroll
            for (int j = 0; j < 8; ++j) {
                acc[0][j] += a0 * b[j];
                acc[1][j] += a1 * b[j];
                acc[2][j] += a2 * b[j];
                acc[3][j] += a3 * b[j];
            }
        }
    }

    float wsum[4];
    #pragma unroll
    for (int i = 0; i < 4; ++i) {
        float p = 0.f;
        #pragma unroll
        for (int j = 0; j < 8; ++j) {
            int f = tf * 8 + j;
            float v = acc[i][j] + be_l[f];
            float m = silu(v);
            acc[i][j] = m;
            p += m * s_wx[f];
        }
        wsum[i] = p;
    }
    #pragma unroll
    for (int off = 1; off < 16; off <<= 1) {
        #pragma unroll
        for (int i = 0; i < 4; ++i) wsum[i] += __shfl_xor(wsum[i], off);
    }
    float bxv = bx_l[0];
    if (tf < 3) {
        #pragma unroll
        for (int i = 0; i < 4; ++i) {
            int e = te * 4 + i;
            float w2 = wsum[i] + bxv;
            atomicAdd(&agg_x[s_dst[e] * 3 + tf], s_diff[e][tf] * w2);
        }
    }
    #pragma unroll
    for (int i = 0; i < 4; ++i) {
        int d = s_dst[te * 4 + i];
        #pragma unroll
        for (int j = 0; j < 8; ++j)
            atomicAdd(&agg_m[d * HID + tf * 8 + j], acc[i][j]);
    }
}

__global__ __launch_bounds__(128) void node_update_fb_kernel(
    float* __restrict__ h, float* __restrict__ x,
    const float* __restrict__ agg_m, const float* __restrict__ agg_x,
    const float* __restrict__ cnt,
    const float* __restrict__ Wh_l, const float* __restrict__ bh_l)
{
    __shared__ float s_in[256][20];
    int n0 = blockIdx.x * 16;
    int tx = threadIdx.x;
    for (int idx = tx; idx < 16 * HID; idx += 128) {
        int i = idx >> 7, k = idx & 127;
        s_in[k][i] = h[(n0 + i) * HID + k];
    }
    for (int idx = tx; idx < 16 * HID; idx += 128) {
        int i = idx >> 7, k = idx & 127;
        s_in[HID + k][i] = agg_m[(n0 + i) * HID + k];
    }
    __syncthreads();
    float acc[16];
    float bv = bh_l[tx];
    #pragma unroll
    for (int i = 0; i < 16; ++i) acc[i] = bv;
    for (int k = 0; k < 256; ++k) {
        float w = Wh_l[k * HID + tx];
        float4 f0 = *(const float4*)&s_in[k][0];
        float4 f1 = *(const float4*)&s_in[k][4];
        float4 f2 = *(const float4*)&s_in[k][8];
        float4 f3 = *(const float4*)&s_in[k][12];
        acc[0] += f0.x*w; acc[1] += f0.y*w; acc[2] += f0.z*w; acc[3] += f0.w*w;
        acc[4] += f1.x*w; acc[5] += f1.y*w; acc[6] += f1.z*w; acc[7] += f1.w*w;
        acc[8] += f2.x*w; acc[9] += f2.y*w; acc[10]+= f2.z*w; acc[11]+= f2.w*w;
        acc[12]+= f3.x*w; acc[13]+= f3.y*w; acc[14]+= f3.z*w; acc[15]+= f3.w*w;
    }
    #pragma unroll
    for (int i = 0; i < 16; ++i) {
        float v = acc[i];
        h[(n0 + i) * HID + tx] = s_in[tx][i] + silu(v);
    }
    if (tx < 48) {
        int i = tx / 3, c = tx % 3;
        int n = n0 + i;
        x[n * 3 + c] += agg_x[n * 3 + c] / (cnt[n] + 1.f);
    }
}

__global__ __launch_bounds__(64) void final_fb_kernel(
    const float* __restrict__ h, const float* __restrict__ x,
    const int* __restrict__ gmask,
    const float* __restrict__ W, const float* __restrict__ b,
    float* __restrict__ out)
{
    __shared__ float s_h[8][HID];
    int n0 = blockIdx.x * 8;
    int tx = threadIdx.x;
    for (int idx = tx; idx < 8 * HID; idx += 64) {
        int i = idx >> 7, k = idx & 127;
        s_h[i][k] = h[(n0 + i) * HID + k];
    }
    __syncthreads();
    float acc[8];
    float bv = b[tx];
    #pragma unroll
    for (int i = 0; i < 8; ++i) acc[i] = bv;
    for (int k = 0; k < HID; ++k) {
        float w = W[k * IN_DIM + tx];
        #pragma unroll
        for (int i = 0; i < 8; ++i) acc[i] += s_h[i][k] * w;
    }
    #pragma unroll
    for (int i = 0; i < 8; ++i) {
        int n = n0 + i;
        out[n * IN_DIM + tx] = gmask[n] ? acc[i] : 0.f;
    }
    if (tx < 24) {
        int i = tx / 3, c = tx % 3;
        int n = n0 + i;
        out[NN * IN_DIM + n * 3 + c] = gmask[n] ? x[n * 3 + c] : 0.f;
    }
}

extern "C" void kernel_launch(void* const* d_in, const int* in_sizes, int n_in,
                              void* d_out, int out_size, void* d_ws, size_t ws_size,
                              hipStream_t stream) {
    const float* H_t   = (const float*)d_in[0];
    const float* X_t   = (const float*)d_in[1];
    const float* cond  = (const float*)d_in[2];
    const float* t_in  = (const float*)d_in[3];
    const int*   edges = (const int*)d_in[4];
    const int*   etype = (const int*)d_in[5];
    const int*   gmask = (const int*)d_in[6];
    const float* W0 = (const float*)d_in[8];
    const float* b0 = (const float*)d_in[9];
    const float* W1 = (const float*)d_in[10];
    const float* b1 = (const float*)d_in[11];
    const float* W2 = (const float*)d_in[12];
    const float* b2 = (const float*)d_in[13];
    const float* edge_table = (const float*)d_in[14];
    const float* We = (const float*)d_in[15];
    const float* be = (const float*)d_in[16];
    const float* Wx = (const float*)d_in[17];
    const float* bx = (const float*)d_in[18];
    const float* Wh = (const float*)d_in[19];
    const float* bh = (const float*)d_in[20];
    const float* h2i_W = (const float*)d_in[21];
    const float* h2i_b = (const float*)d_in[22];

    char* p = (char*)d_ws;
    float* h = (float*)p;           p += (size_t)NN * HID * 4;
    u16* h_bf = (u16*)p;            p += (size_t)NN * HID * 2;
    float* x = (float*)p;           p += (size_t)NN * 3 * 4;
    float* wdiff = (float*)p;       p += (size_t)NE * 3 * 4;
    u16* msg = (u16*)p;             p += (size_t)NE * HID * 2;
    u16* Cbf = (u16*)p;             p += (size_t)NN * 256 * 2;
    u16* Bpack = (u16*)p;           p += (size_t)PACK_TOT * 2;
    float* tv = (float*)p;          p += (size_t)768 * 4;
    float* wed2 = (float*)p;        p += (size_t)384 * 4;
    int* row_start = (int*)p;       p += (size_t)(NN + 4) * 4;
    int* deg = (int*)p;             p += (size_t)NN * 4;
    int* head = (int*)p;            p += (size_t)NN * 4;
    int* src_s = (int*)p;           p += (size_t)NE * 4;
    int* dst_s = (int*)p;           p += (size_t)NE * 4;
    int* et_s = (int*)p;            p += (size_t)NE * 4;
    size_t need = (size_t)(p - (char*)d_ws);

    if (ws_size >= need) {
        hipMemsetAsync(deg, 0, NN * sizeof(int), stream);
        hist_kernel<<<256, 256, 0, stream>>>(X_t, edges, x, deg);
        scan_kernel<<<1, 256, 0, stream>>>(deg, row_start, head);
        scatter_kernel<<<256, 256, 0, stream>>>(edges, etype, head, src_s, dst_s, et_s);
        pack_all_kernel<<<(PACK_TOT + 255) / 256, 256, 0, stream>>>(
            We, W0, W1, W2, Wh, h2i_W, Bpack);
        precomp_tv_kernel<<<5, 256, 0, stream>>>(edge_table, We, be, tv, wed2);
        node_mlp_mfma_kernel<<<NB64, 256, 0, stream>>>(
            H_t, cond, t_in,
            Bpack + OFF_W0, b0, Bpack + OFF_W1, b1, Bpack + OFF_W2, b2,
            h, h_bf);
        for (int l = 0; l < 3; ++l) {
            cvec_kernel<<<NB64, 256, 0, stream>>>(
                h_bf, Bpack + OFF_WE + (size_t)l * 40960, Cbf);
            edge_pass_kernel<<<NE / 64, 256, 0, stream>>>(
                Cbf, x, src_s, dst_s, et_s,
                tv + (size_t)l * 256, wed2 + (size_t)l * 128,
                Wx + l * HID, bx + l, msg, wdiff);
            node_update_mfma_kernel<<<NN / NUB, 256, 0, stream>>>(
                h, h_bf, x, msg, wdiff, row_start,
                Bpack + OFF_WH + (size_t)l * 32768, bh + l * HID);
        }
        final_mfma_kernel<<<NB64, 256, 0, stream>>>(
            h_bf, x, gmask, Bpack + OFF_H2I, h2i_b, (float*)d_out);
    } else {
        // fallback: scalar atomic path (~21 MB)
        float* ws    = (float*)d_ws;
        float* fh    = ws;
        float* fx    = fh + NN * HID;
        float* cnt   = fx + NN * 3;
        float* fagg_m = cnt + NN;
        float* fagg_x = fagg_m + NN * HID;

        hipMemsetAsync(cnt, 0, NN * sizeof(float), stream);
        init_fb_kernel<<<256, 256, 0, stream>>>(X_t, edges, fx, cnt);
        node_mlp_kernel<<<NN / 16, 128, 0, stream>>>(H_t, cond, t_in,
                                                     W0, b0, W1, b1, W2, b2, fh);
        for (int l = 0; l < 3; ++l) {
            hipMemsetAsync(fagg_m, 0, (size_t)NN * 131 * sizeof(float), stream);
            edge_gemm_fb_kernel<<<NE / TILE_E, 256, 0, stream>>>(
                fh, fx, edges, etype, edge_table,
                We + (size_t)l * DE * HID, be + l * HID,
                Wx + l * HID, bx + l, fagg_m, fagg_x);
            node_update_fb_kernel<<<NN / 16, 128, 0, stream>>>(
                fh, fx, fagg_m, fagg_x, cnt,
                Wh + (size_t)l * 256 * HID, bh + l * HID);
        }
        final_fb_kernel<<<NN / 8, 64, 0, stream>>>(fh, fx, gmask, h2i_W, h2i_b, (float*)d_out);
    }
}

// Round 12
// 431.767 us; speedup vs baseline: 1.1992x; 1.1992x over previous
//
#include <hip/hip_runtime.h>
#include <math.h>

#define NN 20000
#define NE 256000
#define IN_DIM 64
#define HID 128
#define DE 289     // 2*HID + 1 + 32
#define D0 320     // IN_DIM + 2*HID
#define TILE_E 64
#define NB64 313   // ceil(NN/64)
#define NUB 16     // nodes per block (fused node kernel)

typedef unsigned short u16;
typedef unsigned int u32;
typedef unsigned long long u64;
typedef __attribute__((ext_vector_type(8))) short short8;
typedef __attribute__((ext_vector_type(4))) float float4v;

// Bpack layout offsets (u16 elements)
#define OFF_WE   0          // 3 x 40960 (K=289 pad 320, N=128) — tiles 0..3 = We rows 0..255
#define OFF_W0   122880     // 40960 (K=320, N=128)
#define OFF_W1   163840     // 16384 (K=128, N=128)
#define OFF_W2   180224     // 16384
#define OFF_WH   196608     // 3 x 32768 (K=256, N=128)
#define OFF_H2I  294912     // 8192 (K=128, N=64)
#define PACK_TOT 303104

static __device__ __forceinline__ u16 f2bf(float f) {
    unsigned int u = __float_as_uint(f);
    u += 0x7fffu + ((u >> 16) & 1u);
    return (u16)(u >> 16);
}
static __device__ __forceinline__ float bf2f(u16 s) {
    return __uint_as_float(((unsigned int)s) << 16);
}
static __device__ __forceinline__ float bflo(u32 u) { return bf2f((u16)(u & 0xffffu)); }
static __device__ __forceinline__ float bfhi(u32 u) { return bf2f((u16)(u >> 16)); }
static __device__ __forceinline__ uint4 pack8(const float* v) {
    uint4 r;
    r.x = (u32)f2bf(v[0]) | ((u32)f2bf(v[1]) << 16);
    r.y = (u32)f2bf(v[2]) | ((u32)f2bf(v[3]) << 16);
    r.z = (u32)f2bf(v[4]) | ((u32)f2bf(v[5]) << 16);
    r.w = (u32)f2bf(v[6]) | ((u32)f2bf(v[7]) << 16);
    return r;
}
static __device__ __forceinline__ void unpack8(uint4 a, float* o) {
    o[0]=bflo(a.x); o[1]=bfhi(a.x); o[2]=bflo(a.y); o[3]=bfhi(a.y);
    o[4]=bflo(a.z); o[5]=bfhi(a.z); o[6]=bflo(a.w); o[7]=bfhi(a.w);
}
static __device__ __forceinline__ float silu(float v) {
    return v * (1.f / (1.f + __expf(-v)));
}

// ================= CSR build =================
__global__ __launch_bounds__(256) void hist_kernel(
    const float* __restrict__ X_t, const int* __restrict__ edges,
    float* __restrict__ x, int* __restrict__ deg)
{
    int gid = blockIdx.x * blockDim.x + threadIdx.x;
    int stride = gridDim.x * blockDim.x;
    for (int i = gid; i < NN * 3; i += stride) x[i] = X_t[i];
    for (int e = gid; e < NE; e += stride)
        atomicAdd(&deg[edges[NE + e]], 1);
}

__global__ __launch_bounds__(256) void scan_kernel(
    const int* __restrict__ deg, int* __restrict__ row_start, int* __restrict__ head)
{
    __shared__ int s[256];
    int tx = threadIdx.x;
    const int per = (NN + 255) / 256;
    int st = tx * per, en = st + per;
    if (st > NN) st = NN;
    if (en > NN) en = NN;
    int sum = 0;
    for (int i = st; i < en; ++i) sum += deg[i];
    s[tx] = sum;
    __syncthreads();
    for (int off = 1; off < 256; off <<= 1) {
        int t = (tx >= off) ? s[tx - off] : 0;
        __syncthreads();
        s[tx] += t;
        __syncthreads();
    }
    int run = (tx == 0) ? 0 : s[tx - 1];
    for (int i = st; i < en; ++i) {
        row_start[i] = run; head[i] = run; run += deg[i];
    }
    if (tx == 255) row_start[NN] = run;
}

// permute edges into dst-sorted order
__global__ __launch_bounds__(256) void scatter_kernel(
    const int* __restrict__ edges, const int* __restrict__ etype,
    int* __restrict__ head,
    int* __restrict__ src_s, int* __restrict__ dst_s, int* __restrict__ et_s)
{
    int gid = blockIdx.x * blockDim.x + threadIdx.x;
    int stride = gridDim.x * blockDim.x;
    for (int e = gid; e < NE; e += stride) {
        int d = edges[NE + e];
        int p = atomicAdd(&head[d], 1);
        src_s[p] = edges[e];
        dst_s[p] = d;
        et_s[p] = etype[e];
    }
}

// ================= weight frag-order packing =================
__global__ __launch_bounds__(256) void pack_all_kernel(
    const float* __restrict__ We, const float* __restrict__ W0,
    const float* __restrict__ W1, const float* __restrict__ W2,
    const float* __restrict__ Wh, const float* __restrict__ h2i,
    u16* __restrict__ Bp)
{
    int idx = blockIdx.x * 256 + threadIdx.x;
    if (idx >= PACK_TOT) return;
    const float* src; int N = 128, Ksrc; int r;
    if (idx < OFF_W0) {
        int layer = idx / 40960; r = idx - layer * 40960;
        src = We + (size_t)layer * DE * HID; Ksrc = DE;
    } else if (idx < OFF_W1) { r = idx - OFF_W0; src = W0; Ksrc = 320; }
    else if (idx < OFF_W2)   { r = idx - OFF_W1; src = W1; Ksrc = 128; }
    else if (idx < OFF_WH)   { r = idx - OFF_W2; src = W2; Ksrc = 128; }
    else if (idx < OFF_H2I) {
        int t = idx - OFF_WH; int layer = t / 32768; r = t - layer * 32768;
        src = Wh + (size_t)layer * 256 * HID; Ksrc = 256;
    } else { r = idx - OFF_H2I; src = h2i; Ksrc = 128; N = 64; }
    int ntc = N / 16;
    int j = r & 7, lane = (r >> 3) & 63;
    int rem = r >> 9;
    int nt = rem % ntc, ks = rem / ntc;
    int k = ks * 32 + ((lane >> 4) << 3) + j;
    int c = nt * 16 + (lane & 15);
    Bp[idx] = f2bf((k < Ksrc) ? src[(size_t)k * N + c] : 0.f);
}

// ================= edge tail precompute (f32) =================
__global__ __launch_bounds__(256) void precomp_tv_kernel(
    const float* __restrict__ edge_table, const float* __restrict__ We,
    const float* __restrict__ be, float* __restrict__ tv, float* __restrict__ wed2)
{
    int idx = blockIdx.x * 256 + threadIdx.x;
    if (idx < 768) {
        int f = idx & 127, t = (idx >> 7) & 1, l = idx >> 8;
        float acc = be[l * 128 + f];
        const float* W = We + (size_t)l * DE * HID;
        #pragma unroll
        for (int k = 0; k < 32; ++k)
            acc += edge_table[t * 32 + k] * W[(size_t)(257 + k) * HID + f];
        tv[l * 256 + t * 128 + f] = acc;
    } else if (idx < 1152) {
        int r = idx - 768;
        int f = r & 127, l = r >> 7;
        wed2[l * 128 + f] = We[(size_t)l * DE * HID + (size_t)256 * HID + f];
    }
}

// ================= per-layer edge geometry: (dx,dy,dz,d2) =================
__global__ __launch_bounds__(256) void geom_kernel(
    const float* __restrict__ x,
    const int* __restrict__ src_s, const int* __restrict__ dst_s,
    float4* __restrict__ geom)
{
    int e = blockIdx.x * 256 + threadIdx.x;
    if (e >= NE) return;
    int s = src_s[e], d = dst_s[e];
    float dx = x[s*3+0]-x[d*3+0], dy = x[s*3+1]-x[d*3+1], dz = x[s*3+2]-x[d*3+2];
    geom[e] = make_float4(dx, dy, dz, dx*dx + dy*dy + dz*dz);
}

// ================= node MLP: MFMA, 64 nodes/block =================
__global__ __launch_bounds__(256) void node_mlp_mfma_kernel(
    const float* __restrict__ H_t, const float* __restrict__ cond,
    const float* __restrict__ t_in,
    const u16* __restrict__ W0p, const float* __restrict__ b0,
    const u16* __restrict__ W1p, const float* __restrict__ b1,
    const u16* __restrict__ W2p, const float* __restrict__ b2,
    float* __restrict__ h, u16* __restrict__ h_bf)
{
    __shared__ u16 s_A[64 * 64];
    __shared__ u16 s_B[64 * 128];
    __shared__ u16 s_h[64 * 128];
    __shared__ float s_t[64];

    int tx = threadIdx.x;
    int n0 = blockIdx.x * 64;
    int l = tx & 63, w = tx >> 6;
    int mt_base = (w & 1) * 2, nt_base = (w >> 1) * 4;
    const float cfr = -logf(10000.f) / 63.f;

    if (tx < 64) s_t[tx] = (n0 + tx < NN) ? t_in[n0 + tx] : 0.f;

    float4v acc[2][4];
    #pragma unroll
    for (int mi = 0; mi < 2; ++mi)
        #pragma unroll
        for (int ni = 0; ni < 4; ++ni) acc[mi][ni] = (float4v){0.f,0.f,0.f,0.f};

    for (int t = 0; t < 5; ++t) {
        __syncthreads();
        #pragma unroll
        for (int it = 0; it < 2; ++it) {
            int flat = it * 256 + tx;
            int n = flat >> 3, sl = flat & 7;
            int c = sl ^ (n & 7);
            int k0 = t * 64 + c * 8;
            float tv8[8];
            int gn = n0 + n;
            if (gn < NN) {
                if (k0 < 192) {
                    const float* src = (k0 < 64) ? &H_t[(size_t)gn * IN_DIM + k0]
                                                 : &cond[(size_t)gn * HID + (k0 - 64)];
                    float4 a = *(const float4*)src;
                    float4 b = *(const float4*)(src + 4);
                    tv8[0]=a.x; tv8[1]=a.y; tv8[2]=a.z; tv8[3]=a.w;
                    tv8[4]=b.x; tv8[5]=b.y; tv8[6]=b.z; tv8[7]=b.w;
                } else {
                    float tv = s_t[n];
                    int jj = (k0 - 192) & 63;
                    bool is_sin = (k0 < 256);
                    #pragma unroll
                    for (int jx = 0; jx < 8; ++jx) {
                        float ang = tv * __expf(cfr * (float)(jj + jx));
                        tv8[jx] = is_sin ? __sinf(ang) : __cosf(ang);
                    }
                }
            } else {
                #pragma unroll
                for (int jx = 0; jx < 8; ++jx) tv8[jx] = 0.f;
            }
            *(uint4*)&s_A[n * 64 + sl * 8] = pack8(tv8);
        }
        #pragma unroll
        for (int it = 0; it < 4; ++it) {
            int flat = it * 256 + tx;
            ((uint4*)s_B)[flat] = ((const uint4*)(W0p + (size_t)t * 8192))[flat];
        }
        __syncthreads();
        #pragma unroll
        for (int s = 0; s < 2; ++s) {
            short8 af[2], bfv[4];
            #pragma unroll
            for (int mi = 0; mi < 2; ++mi) {
                int m = (mt_base + mi) * 16 + (l & 15);
                int c = s * 4 + (l >> 4);
                int slot = c ^ (l & 7);
                af[mi] = *(const short8*)(s_A + m * 64 + slot * 8);
            }
            #pragma unroll
            for (int ni = 0; ni < 4; ++ni)
                bfv[ni] = *(const short8*)(s_B + ((s * 8 + nt_base + ni) * 64 + l) * 8);
            #pragma unroll
            for (int mi = 0; mi < 2; ++mi)
                #pragma unroll
                for (int ni = 0; ni < 4; ++ni)
                    acc[mi][ni] = __builtin_amdgcn_mfma_f32_16x16x32_bf16(
                        af[mi], bfv[ni], acc[mi][ni], 0, 0, 0);
        }
    }
    #pragma unroll
    for (int mi = 0; mi < 2; ++mi) {
        #pragma unroll
        for (int ni = 0; ni < 4; ++ni) {
            int f = (nt_base + ni) * 16 + (l & 15);
            float bv = b0[f];
            #pragma unroll
            for (int r = 0; r < 4; ++r) {
                int m = (mt_base + mi) * 16 + (l >> 4) * 4 + r;
                float v = fmaxf(acc[mi][ni][r] + bv, 0.f);
                int slot = (f >> 3) ^ (m & 7);
                s_h[m * 128 + slot * 8 + (f & 7)] = f2bf(v);
            }
            acc[mi][ni] = (float4v){0.f,0.f,0.f,0.f};
        }
    }
    for (int t = 0; t < 2; ++t) {
        __syncthreads();
        #pragma unroll
        for (int it = 0; it < 4; ++it) {
            int flat = it * 256 + tx;
            ((uint4*)s_B)[flat] = ((const uint4*)(W1p + (size_t)t * 8192))[flat];
        }
        __syncthreads();
        #pragma unroll
        for (int s = 0; s < 2; ++s) {
            short8 af[2], bfv[4];
            #pragma unroll
            for (int mi = 0; mi < 2; ++mi) {
                int m = (mt_base + mi) * 16 + (l & 15);
                int c = t * 8 + s * 4 + (l >> 4);
                int slot = c ^ (l & 7);
                af[mi] = *(const short8*)(s_h + m * 128 + slot * 8);
            }
            #pragma unroll
            for (int ni = 0; ni < 4; ++ni)
                bfv[ni] = *(const short8*)(s_B + ((s * 8 + nt_base + ni) * 64 + l) * 8);
            #pragma unroll
            for (int mi = 0; mi < 2; ++mi)
                #pragma unroll
                for (int ni = 0; ni < 4; ++ni)
                    acc[mi][ni] = __builtin_amdgcn_mfma_f32_16x16x32_bf16(
                        af[mi], bfv[ni], acc[mi][ni], 0, 0, 0);
        }
    }
    __syncthreads();
    #pragma unroll
    for (int mi = 0; mi < 2; ++mi) {
        #pragma unroll
        for (int ni = 0; ni < 4; ++ni) {
            int f = (nt_base + ni) * 16 + (l & 15);
            float bv = b1[f];
            #pragma unroll
            for (int r = 0; r < 4; ++r) {
                int m = (mt_base + mi) * 16 + (l >> 4) * 4 + r;
                float v = fmaxf(acc[mi][ni][r] + bv, 0.f);
                int slot = (f >> 3) ^ (m & 7);
                s_h[m * 128 + slot * 8 + (f & 7)] = f2bf(v);
            }
            acc[mi][ni] = (float4v){0.f,0.f,0.f,0.f};
        }
    }
    for (int t = 0; t < 2; ++t) {
        __syncthreads();
        #pragma unroll
        for (int it = 0; it < 4; ++it) {
            int flat = it * 256 + tx;
            ((uint4*)s_B)[flat] = ((const uint4*)(W2p + (size_t)t * 8192))[flat];
        }
        __syncthreads();
        #pragma unroll
        for (int s = 0; s < 2; ++s) {
            short8 af[2], bfv[4];
            #pragma unroll
            for (int mi = 0; mi < 2; ++mi) {
                int m = (mt_base + mi) * 16 + (l & 15);
                int c = t * 8 + s * 4 + (l >> 4);
                int slot = c ^ (l & 7);
                af[mi] = *(const short8*)(s_h + m * 128 + slot * 8);
            }
            #pragma unroll
            for (int ni = 0; ni < 4; ++ni)
                bfv[ni] = *(const short8*)(s_B + ((s * 8 + nt_base + ni) * 64 + l) * 8);
            #pragma unroll
            for (int mi = 0; mi < 2; ++mi)
                #pragma unroll
                for (int ni = 0; ni < 4; ++ni)
                    acc[mi][ni] = __builtin_amdgcn_mfma_f32_16x16x32_bf16(
                        af[mi], bfv[ni], acc[mi][ni], 0, 0, 0);
        }
    }
    #pragma unroll
    for (int mi = 0; mi < 2; ++mi) {
        #pragma unroll
        for (int ni = 0; ni < 4; ++ni) {
            int f = (nt_base + ni) * 16 + (l & 15);
            float bv = b2[f];
            #pragma unroll
            for (int r = 0; r < 4; ++r) {
                int m = (mt_base + mi) * 16 + (l >> 4) * 4 + r;
                int gn = n0 + m;
                if (gn < NN) {
                    float v = acc[mi][ni][r] + bv;
                    h[(size_t)gn * HID + f] = v;
                    h_bf[(size_t)gn * HID + f] = f2bf(v);
                }
            }
        }
    }
}

// ================= cvec: C[n][0:128]=h@We_src, C[n][128:256]=h@We_dst (bf16 out) =================
__global__ __launch_bounds__(256) void cvec_kernel(
    const u16* __restrict__ h_bf, const u16* __restrict__ WEp,
    u16* __restrict__ Cbf)
{
    __shared__ u16 s_A[64 * 64];
    __shared__ u16 s_B[64 * 128];

    int tx = threadIdx.x;
    int n0 = blockIdx.x * 64;
    int l = tx & 63, w = tx >> 6;
    int mt_base = (w & 1) * 2, nt_base = (w >> 1) * 4;

    float4v acc[2][2][4];  // [side][mi][ni]
    #pragma unroll
    for (int sd = 0; sd < 2; ++sd)
        #pragma unroll
        for (int mi = 0; mi < 2; ++mi)
            #pragma unroll
            for (int ni = 0; ni < 4; ++ni)
                acc[sd][mi][ni] = (float4v){0.f,0.f,0.f,0.f};

    for (int t = 0; t < 4; ++t) {
        __syncthreads();
        #pragma unroll
        for (int it = 0; it < 2; ++it) {
            int flat = it * 256 + tx;
            int n = flat >> 3, sl = flat & 7;
            int c = sl ^ (n & 7);
            int gn = n0 + n;
            uint4 v = make_uint4(0,0,0,0);
            if (gn < NN) v = *(const uint4*)(h_bf + (size_t)gn * 128 + (t & 1) * 64 + c * 8);
            *(uint4*)&s_A[n * 64 + sl * 8] = v;
        }
        #pragma unroll
        for (int it = 0; it < 4; ++it) {
            int flat = it * 256 + tx;
            ((uint4*)s_B)[flat] = ((const uint4*)(WEp + (size_t)t * 8192))[flat];
        }
        __syncthreads();
        int sd = t >> 1;
        #pragma unroll
        for (int s = 0; s < 2; ++s) {
            short8 af[2], bfv[4];
            #pragma unroll
            for (int mi = 0; mi < 2; ++mi) {
                int m = (mt_base + mi) * 16 + (l & 15);
                int c = s * 4 + (l >> 4);
                int slot = c ^ (l & 7);
                af[mi] = *(const short8*)(s_A + m * 64 + slot * 8);
            }
            #pragma unroll
            for (int ni = 0; ni < 4; ++ni)
                bfv[ni] = *(const short8*)(s_B + ((s * 8 + nt_base + ni) * 64 + l) * 8);
            #pragma unroll
            for (int mi = 0; mi < 2; ++mi)
                #pragma unroll
                for (int ni = 0; ni < 4; ++ni)
                    acc[sd][mi][ni] = __builtin_amdgcn_mfma_f32_16x16x32_bf16(
                        af[mi], bfv[ni], acc[sd][mi][ni], 0, 0, 0);
        }
    }
    #pragma unroll
    for (int sd = 0; sd < 2; ++sd) {
        #pragma unroll
        for (int mi = 0; mi < 2; ++mi) {
            #pragma unroll
            for (int ni = 0; ni < 4; ++ni) {
                int f = sd * 128 + (nt_base + ni) * 16 + (l & 15);
                #pragma unroll
                for (int r = 0; r < 4; ++r) {
                    int m = (mt_base + mi) * 16 + (l >> 4) * 4 + r;
                    int gn = n0 + m;
                    if (gn < NN)
                        Cbf[(size_t)gn * 256 + f] = f2bf(acc[sd][mi][ni][r]);
                }
            }
        }
    }
}

// ================= fused node update: inline messages + CSR agg + Wh MFMA =================
// 16 nodes/block; thread (i = tx>>4, p = tx&15) covers 8 feats of node i.
__global__ __launch_bounds__(256) void node_fused_kernel(
    float* __restrict__ h, u16* __restrict__ h_bf, float* __restrict__ x,
    const u16* __restrict__ Cbf, const float4* __restrict__ geom,
    const int* __restrict__ src_s, const int* __restrict__ et_s,
    const int* __restrict__ row_start,
    const float* __restrict__ tv_l, const float* __restrict__ wed2_l,
    const float* __restrict__ Wx_l, const float* __restrict__ bx_l,
    const u16* __restrict__ Whp_l, const float* __restrict__ bh_l)
{
    __shared__ u16 s_A[NUB * 256];   // 8 KB: [node][256k] xor-swizzled: h | agg
    __shared__ u16 s_B[64 * 128];    // 16 KB
    __shared__ int s_rs[NUB + 1];

    int tx = threadIdx.x;
    int n0 = blockIdx.x * NUB;
    int l = tx & 63, w = tx >> 6;
    int nt_base = w * 2;

    if (tx < NUB + 1) s_rs[tx] = row_start[n0 + tx];
    // stage h_bf (chunks 0..15)
    {
        int n = tx >> 4, c = tx & 15;
        int slot = c ^ (n & 7);
        uint4 v = *(const uint4*)(h_bf + (size_t)(n0 + n) * 128 + c * 8);
        *(uint4*)&s_A[n * 256 + slot * 8] = v;
    }
    __syncthreads();
    // fused message + aggregation
    {
        int i = tx >> 4, p = tx & 15;
        int gn = n0 + i;
        int rs = s_rs[i], re = s_rs[i + 1];
        float cdv[8], tv0[8], tv1[8], wed[8], wx[8];
        unpack8(*(const uint4*)(Cbf + (size_t)gn * 256 + 128 + p * 8), cdv);
        #pragma unroll
        for (int q = 0; q < 2; ++q) {
            float4 a0 = *(const float4*)(tv_l + p * 8 + q * 4);
            float4 a1 = *(const float4*)(tv_l + 128 + p * 8 + q * 4);
            float4 a2 = *(const float4*)(wed2_l + p * 8 + q * 4);
            float4 a3 = *(const float4*)(Wx_l + p * 8 + q * 4);
            tv0[q*4+0]=a0.x; tv0[q*4+1]=a0.y; tv0[q*4+2]=a0.z; tv0[q*4+3]=a0.w;
            tv1[q*4+0]=a1.x; tv1[q*4+1]=a1.y; tv1[q*4+2]=a1.z; tv1[q*4+3]=a1.w;
            wed[q*4+0]=a2.x; wed[q*4+1]=a2.y; wed[q*4+2]=a2.z; wed[q*4+3]=a2.w;
            wx[q*4+0]=a3.x; wx[q*4+1]=a3.y; wx[q*4+2]=a3.z; wx[q*4+3]=a3.w;
        }
        float bxv = bx_l[0];
        float ag[8];
        #pragma unroll
        for (int q = 0; q < 8; ++q) ag[q] = 0.f;
        float sxx = 0.f;
        for (int j = rs; j < re; ++j) {
            int sj = src_s[j];
            int et = et_s[j];
            float4 g = geom[j];
            float av[8];
            unpack8(*(const uint4*)(Cbf + (size_t)sj * 256 + p * 8), av);
            float wpart = 0.f;
            #pragma unroll
            for (int f = 0; f < 8; ++f) {
                float tvf = et ? tv1[f] : tv0[f];
                float v = av[f] + cdv[f] + tvf + g.w * wed[f];
                float m = silu(v);
                ag[f] += m;
                wpart += m * wx[f];
            }
            // reduce over the 16 lanes of this node
            wpart += __shfl_xor(wpart, 1);
            wpart += __shfl_xor(wpart, 2);
            wpart += __shfl_xor(wpart, 4);
            wpart += __shfl_xor(wpart, 8);
            if (p < 3) {
                float gc = (p == 0) ? g.x : ((p == 1) ? g.y : g.z);
                sxx += gc * (wpart + bxv);
            }
        }
        int c2 = 16 + p;
        int slot = c2 ^ (i & 7);
        *(uint4*)&s_A[i * 256 + slot * 8] = pack8(ag);
        if (p < 3)
            x[gn * 3 + p] += sxx / ((float)(re - rs) + 1.f);
    }

    float4v acc[2];
    #pragma unroll
    for (int ni = 0; ni < 2; ++ni) acc[ni] = (float4v){0.f,0.f,0.f,0.f};

    for (int t = 0; t < 4; ++t) {
        __syncthreads();
        #pragma unroll
        for (int it = 0; it < 4; ++it) {
            int flat = it * 256 + tx;
            ((uint4*)s_B)[flat] = ((const uint4*)(Whp_l + (size_t)t * 8192))[flat];
        }
        __syncthreads();
        #pragma unroll
        for (int s = 0; s < 2; ++s) {
            short8 af, bfv[2];
            {
                int m = l & 15;
                int c = t * 8 + s * 4 + (l >> 4);
                int slot = c ^ (l & 7);
                af = *(const short8*)(s_A + m * 256 + slot * 8);
            }
            #pragma unroll
            for (int ni = 0; ni < 2; ++ni)
                bfv[ni] = *(const short8*)(s_B + ((s * 8 + nt_base + ni) * 64 + l) * 8);
            #pragma unroll
            for (int ni = 0; ni < 2; ++ni)
                acc[ni] = __builtin_amdgcn_mfma_f32_16x16x32_bf16(
                    af, bfv[ni], acc[ni], 0, 0, 0);
        }
    }
    #pragma unroll
    for (int ni = 0; ni < 2; ++ni) {
        int f = (nt_base + ni) * 16 + (l & 15);
        float bv = bh_l[f];
        #pragma unroll
        for (int r = 0; r < 4; ++r) {
            int m = (l >> 4) * 4 + r;
            int gn = n0 + m;
            float v = acc[ni][r] + bv;
            float hn = h[(size_t)gn * HID + f] + silu(v);
            h[(size_t)gn * HID + f] = hn;
            h_bf[(size_t)gn * HID + f] = f2bf(hn);
        }
    }
}

// ================= final: MFMA h2i, 64 nodes/block =================
__global__ __launch_bounds__(256) void final_mfma_kernel(
    const u16* __restrict__ h_bf, const float* __restrict__ x,
    const int* __restrict__ gmask,
    const u16* __restrict__ h2ip, const float* __restrict__ b,
    float* __restrict__ out)
{
    __shared__ u16 s_A[64 * 128];
    __shared__ u16 s_B[4096];

    int tx = threadIdx.x;
    int n0 = blockIdx.x * 64;
    int l = tx & 63, w = tx >> 6;
    int mt_base = (w & 1) * 2, nt_base = (w >> 1) * 2;

    #pragma unroll
    for (int it = 0; it < 4; ++it) {
        int flat = it * 256 + tx;
        int n = flat >> 4, c = flat & 15;
        int slot = c ^ (n & 7);
        int gn = n0 + n;
        uint4 v = make_uint4(0,0,0,0);
        if (gn < NN) v = *(const uint4*)(h_bf + (size_t)gn * 128 + c * 8);
        *(uint4*)&s_A[n * 128 + slot * 8] = v;
    }

    float4v acc[2][2];
    #pragma unroll
    for (int mi = 0; mi < 2; ++mi)
        #pragma unroll
        for (int ni = 0; ni < 2; ++ni) acc[mi][ni] = (float4v){0.f,0.f,0.f,0.f};

    for (int t = 0; t < 2; ++t) {
        __syncthreads();
        #pragma unroll
        for (int it = 0; it < 2; ++it) {
            int flat = it * 256 + tx;
            ((uint4*)s_B)[flat] = ((const uint4*)(h2ip + (size_t)t * 4096))[flat];
        }
        __syncthreads();
        #pragma unroll
        for (int s = 0; s < 2; ++s) {
            short8 af[2], bfv[2];
            #pragma unroll
            for (int mi = 0; mi < 2; ++mi) {
                int m = (mt_base + mi) * 16 + (l & 15);
                int c = t * 8 + s * 4 + (l >> 4);
                int slot = c ^ (l & 7);
                af[mi] = *(const short8*)(s_A + m * 128 + slot * 8);
            }
            #pragma unroll
            for (int ni = 0; ni < 2; ++ni)
                bfv[ni] = *(const short8*)(s_B + ((s * 4 + nt_base + ni) * 64 + l) * 8);
            #pragma unroll
            for (int mi = 0; mi < 2; ++mi)
                #pragma unroll
                for (int ni = 0; ni < 2; ++ni)
                    acc[mi][ni] = __builtin_amdgcn_mfma_f32_16x16x32_bf16(
                        af[mi], bfv[ni], acc[mi][ni], 0, 0, 0);
        }
    }
    #pragma unroll
    for (int mi = 0; mi < 2; ++mi) {
        #pragma unroll
        for (int ni = 0; ni < 2; ++ni) {
            int f = (nt_base + ni) * 16 + (l & 15);
            float bv = b[f];
            #pragma unroll
            for (int r = 0; r < 4; ++r) {
                int m = (mt_base + mi) * 16 + (l >> 4) * 4 + r;
                int gn = n0 + m;
                if (gn < NN)
                    out[(size_t)gn * IN_DIM + f] = gmask[gn] ? (acc[mi][ni][r] + bv) : 0.f;
            }
        }
    }
    if (tx < 192) {
        int i = tx / 3, c = tx % 3;
        int gn = n0 + i;
        if (gn < NN)
            out[(size_t)NN * IN_DIM + gn * 3 + c] = gmask[gn] ? x[gn * 3 + c] : 0.f;
    }
}

// ================= fallback path (atomic, scalar; used only if ws too small) =================
__global__ __launch_bounds__(256) void init_fb_kernel(
    const float* __restrict__ X_t, const int* __restrict__ edges,
    float* __restrict__ x, float* __restrict__ cnt)
{
    int gid = blockIdx.x * blockDim.x + threadIdx.x;
    int stride = gridDim.x * blockDim.x;
    for (int i = gid; i < NN * 3; i += stride) x[i] = X_t[i];
    for (int e = gid; e < NE; e += stride)
        atomicAdd(&cnt[edges[NE + e]], 1.0f);
}

__global__ __launch_bounds__(128) void node_mlp_kernel(
    const float* __restrict__ H_t, const float* __restrict__ cond,
    const float* __restrict__ t_in,
    const float* __restrict__ W0, const float* __restrict__ b0,
    const float* __restrict__ W1, const float* __restrict__ b1,
    const float* __restrict__ W2, const float* __restrict__ b2,
    float* __restrict__ h)
{
    __shared__ float s_feat[D0][20];
    __shared__ float s_h0[HID][20];
    __shared__ float s_h1[HID][20];
    int n0 = blockIdx.x * 16;
    int tx = threadIdx.x;

    for (int idx = tx; idx < 16 * IN_DIM; idx += 128) {
        int i = idx >> 6, k = idx & 63;
        s_feat[k][i] = H_t[(n0 + i) * IN_DIM + k];
    }
    for (int idx = tx; idx < 16 * HID; idx += 128) {
        int i = idx >> 7, k = idx & 127;
        s_feat[IN_DIM + k][i] = cond[(n0 + i) * HID + k];
    }
    const float cfr = -logf(10000.f) / 63.f;
    for (int idx = tx; idx < 16 * HID; idx += 128) {
        int i = idx >> 7, k = idx & 127;
        float tv = t_in[n0 + i];
        int jj = k & 63;
        float ang = tv * __expf(cfr * (float)jj);
        s_feat[IN_DIM + HID + k][i] = (k < 64) ? __sinf(ang) : __cosf(ang);
    }
    __syncthreads();

    float acc[16];
    {
        float bv = b0[tx];
        #pragma unroll
        for (int i = 0; i < 16; ++i) acc[i] = bv;
        for (int k = 0; k < D0; ++k) {
            float w = W0[k * HID + tx];
            float4 f0 = *(const float4*)&s_feat[k][0];
            float4 f1 = *(const float4*)&s_feat[k][4];
            float4 f2 = *(const float4*)&s_feat[k][8];
            float4 f3 = *(const float4*)&s_feat[k][12];
            acc[0] += f0.x*w; acc[1] += f0.y*w; acc[2] += f0.z*w; acc[3] += f0.w*w;
            acc[4] += f1.x*w; acc[5] += f1.y*w; acc[6] += f1.z*w; acc[7] += f1.w*w;
            acc[8] += f2.x*w; acc[9] += f2.y*w; acc[10]+= f2.z*w; acc[11]+= f2.w*w;
            acc[12]+= f3.x*w; acc[13]+= f3.y*w; acc[14]+= f3.z*w; acc[15]+= f3.w*w;
        }
        #pragma unroll
        for (int i = 0; i < 16; ++i) s_h0[tx][i] = fmaxf(acc[i], 0.f);
    }
    __syncthreads();
    {
        float bv = b1[tx];
        #pragma unroll
        for (int i = 0; i < 16; ++i) acc[i] = bv;
        for (int k = 0; k < HID; ++k) {
            float w = W1[k * HID + tx];
            float4 f0 = *(const float4*)&s_h0[k][0];
            float4 f1 = *(const float4*)&s_h0[k][4];
            float4 f2 = *(const float4*)&s_h0[k][8];
            float4 f3 = *(const float4*)&s_h0[k][12];
            acc[0] += f0.x*w; acc[1] += f0.y*w; acc[2] += f0.z*w; acc[3] += f0.w*w;
            acc[4] += f1.x*w; acc[5] += f1.y*w; acc[6] += f1.z*w; acc[7] += f1.w*w;
            acc[8] += f2.x*w; acc[9] += f2.y*w; acc[10]+= f2.z*w; acc[11]+= f2.w*w;
            acc[12]+= f3.x*w; acc[13]+= f3.y*w; acc[14]+= f3.z*w; acc[15]+= f3.w*w;
        }
        #pragma unroll
        for (int i = 0; i < 16; ++i) s_h1[tx][i] = fmaxf(acc[i], 0.f);
    }
    __syncthreads();
    {
        float bv = b2[tx];
        #pragma unroll
        for (int i = 0; i < 16; ++i) acc[i] = bv;
        for (int k = 0; k < HID; ++k) {
            float w = W2[k * HID + tx];
            float4 f0 = *(const float4*)&s_h1[k][0];
            float4 f1 = *(const float4*)&s_h1[k][4];
            float4 f2 = *(const float4*)&s_h1[k][8];
            float4 f3 = *(const float4*)&s_h1[k][12];
            acc[0] += f0.x*w; acc[1] += f0.y*w; acc[2] += f0.z*w; acc[3] += f0.w*w;
            acc[4] += f1.x*w; acc[5] += f1.y*w; acc[6] += f1.z*w; acc[7] += f1.w*w;
            acc[8] += f2.x*w; acc[9] += f2.y*w; acc[10]+= f2.z*w; acc[11]+= f2.w*w;
            acc[12]+= f3.x*w; acc[13]+= f3.y*w; acc[14]+= f3.z*w; acc[15]+= f3.w*w;
        }
        #pragma unroll
        for (int i = 0; i < 16; ++i) h[(n0 + i) * HID + tx] = acc[i];
    }
}

__global__ __launch_bounds__(256) void edge_gemm_fb_kernel(
    const float* __restrict__ h, const float* __restrict__ x,
    const int* __restrict__ edges, const int* __restrict__ etype,
    const float* __restrict__ edge_table,
    const float* __restrict__ We_l, const float* __restrict__ be_l,
    const float* __restrict__ Wx_l, const float* __restrict__ bx_l,
    float* __restrict__ agg_m, float* __restrict__ agg_x)
{
    __shared__ int s_src[TILE_E], s_dst[TILE_E];
    __shared__ float s_diff[TILE_E][3];
    __shared__ float s_tail[TILE_E][36];
    __shared__ float s_Af[TILE_E][36];
    __shared__ float s_Bf[33][HID];
    __shared__ float s_wx[HID];

    int e0 = blockIdx.x * TILE_E;
    int tx = threadIdx.x;
    int tf = tx & 15;
    int te = tx >> 4;

    if (tx < TILE_E) {
        int s = edges[e0 + tx];
        int d = edges[NE + e0 + tx];
        s_src[tx] = s; s_dst[tx] = d;
        float dx = x[s * 3 + 0] - x[d * 3 + 0];
        float dy = x[s * 3 + 1] - x[d * 3 + 1];
        float dz = x[s * 3 + 2] - x[d * 3 + 2];
        s_diff[tx][0] = dx; s_diff[tx][1] = dy; s_diff[tx][2] = dz;
        s_tail[tx][0] = dx * dx + dy * dy + dz * dz;
        int et = etype[e0 + tx];
        #pragma unroll
        for (int j = 0; j < 32; ++j) s_tail[tx][1 + j] = edge_table[et * 32 + j];
    }
    if (tx < HID) s_wx[tx] = Wx_l[tx];
    __syncthreads();

    float acc[4][8];
    #pragma unroll
    for (int i = 0; i < 4; ++i)
        #pragma unroll
        for (int j = 0; j < 8; ++j) acc[i][j] = 0.f;

    for (int t = 0; t < 9; ++t) {
        int k0 = t * 32;
        int klen = (t == 8) ? 33 : 32;
        __syncthreads();
        if (t < 8) {
            const bool use_src = (t < 4);
            int kbase = (t & 3) * 32;
            for (int q4 = tx; q4 < TILE_E * 8; q4 += 256) {
                int e = q4 >> 3, q = q4 & 7;
                int row = use_src ? s_src[e] : s_dst[e];
                float4 v = *(const float4*)&h[row * HID + kbase + q * 4];
                *(float4*)&s_Af[e][q * 4] = v;
            }
        }
        for (int q4 = tx; q4 < klen * 32; q4 += 256) {
            int kk = q4 >> 5, c4 = q4 & 31;
            float4 v = *(const float4*)&We_l[(k0 + kk) * HID + c4 * 4];
            *(float4*)&s_Bf[kk][c4 * 4] = v;
        }
        __syncthreads();
        const float (*Asrc)[36] = (t == 8) ? (const float (*)[36])s_tail
                                           : (const float (*)[36])s_Af;
        for (int kk = 0; kk < klen; ++kk) {
            float a0 = Asrc[te * 4 + 0][kk];
            float a1 = Asrc[te * 4 + 1][kk];
            float a2 = Asrc[te * 4 + 2][kk];
            float a3 = Asrc[te * 4 + 3][kk];
            float4 bv0 = *(const float4*)&s_Bf[kk][tf * 8];
            float4 bv1 = *(const float4*)&s_Bf[kk][tf * 8 + 4];
            float b[8] = {bv0.x, bv0.y, bv0.z, bv0.w, bv1.x, bv1.y, bv1.z, bv1.w};
            #pragma unroll
            for (int j = 0; j < 8; ++j) {
                acc[0][j] += a0 * b[j];
                acc[1][j] += a1 * b[j];
                acc[2][j] += a2 * b[j];
                acc[3][j] += a3 * b[j];
            }
        }
    }

    float wsum[4];
    #pragma unroll
    for (int i = 0; i < 4; ++i) {
        float p = 0.f;
        #pragma unroll
        for (int j = 0; j < 8; ++j) {
            int f = tf * 8 + j;
            float v = acc[i][j] + be_l[f];
            float m = silu(v);
            acc[i][j] = m;
            p += m * s_wx[f];
        }
        wsum[i] = p;
    }
    #pragma unroll
    for (int off = 1; off < 16; off <<= 1) {
        #pragma unroll
        for (int i = 0; i < 4; ++i) wsum[i] += __shfl_xor(wsum[i], off);
    }
    float bxv = bx_l[0];
    if (tf < 3) {
        #pragma unroll
        for (int i = 0; i < 4; ++i) {
            int e = te * 4 + i;
            float w2 = wsum[i] + bxv;
            atomicAdd(&agg_x[s_dst[e] * 3 + tf], s_diff[e][tf] * w2);
        }
    }
    #pragma unroll
    for (int i = 0; i < 4; ++i) {
        int d = s_dst[te * 4 + i];
        #pragma unroll
        for (int j = 0; j < 8; ++j)
            atomicAdd(&agg_m[d * HID + tf * 8 + j], acc[i][j]);
    }
}

__global__ __launch_bounds__(128) void node_update_fb_kernel(
    float* __restrict__ h, float* __restrict__ x,
    const float* __restrict__ agg_m, const float* __restrict__ agg_x,
    const float* __restrict__ cnt,
    const float* __restrict__ Wh_l, const float* __restrict__ bh_l)
{
    __shared__ float s_in[256][20];
    int n0 = blockIdx.x * 16;
    int tx = threadIdx.x;
    for (int idx = tx; idx < 16 * HID; idx += 128) {
        int i = idx >> 7, k = idx & 127;
        s_in[k][i] = h[(n0 + i) * HID + k];
    }
    for (int idx = tx; idx < 16 * HID; idx += 128) {
        int i = idx >> 7, k = idx & 127;
        s_in[HID + k][i] = agg_m[(n0 + i) * HID + k];
    }
    __syncthreads();
    float acc[16];
    float bv = bh_l[tx];
    #pragma unroll
    for (int i = 0; i < 16; ++i) acc[i] = bv;
    for (int k = 0; k < 256; ++k) {
        float w = Wh_l[k * HID + tx];
        float4 f0 = *(const float4*)&s_in[k][0];
        float4 f1 = *(const float4*)&s_in[k][4];
        float4 f2 = *(const float4*)&s_in[k][8];
        float4 f3 = *(const float4*)&s_in[k][12];
        acc[0] += f0.x*w; acc[1] += f0.y*w; acc[2] += f0.z*w; acc[3] += f0.w*w;
        acc[4] += f1.x*w; acc[5] += f1.y*w; acc[6] += f1.z*w; acc[7] += f1.w*w;
        acc[8] += f2.x*w; acc[9] += f2.y*w; acc[10]+= f2.z*w; acc[11]+= f2.w*w;
        acc[12]+= f3.x*w; acc[13]+= f3.y*w; acc[14]+= f3.z*w; acc[15]+= f3.w*w;
    }
    #pragma unroll
    for (int i = 0; i < 16; ++i) {
        float v = acc[i];
        h[(n0 + i) * HID + tx] = s_in[tx][i] + silu(v);
    }
    if (tx < 48) {
        int i = tx / 3, c = tx % 3;
        int n = n0 + i;
        x[n * 3 + c] += agg_x[n * 3 + c] / (cnt[n] + 1.f);
    }
}

__global__ __launch_bounds__(64) void final_fb_kernel(
    const float* __restrict__ h, const float* __restrict__ x,
    const int* __restrict__ gmask,
    const float* __restrict__ W, const float* __restrict__ b,
    float* __restrict__ out)
{
    __shared__ float s_h[8][HID];
    int n0 = blockIdx.x * 8;
    int tx = threadIdx.x;
    for (int idx = tx; idx < 8 * HID; idx += 64) {
        int i = idx >> 7, k = idx & 127;
        s_h[i][k] = h[(n0 + i) * HID + k];
    }
    __syncthreads();
    float acc[8];
    float bv = b[tx];
    #pragma unroll
    for (int i = 0; i < 8; ++i) acc[i] = bv;
    for (int k = 0; k < HID; ++k) {
        float w = W[k * IN_DIM + tx];
        #pragma unroll
        for (int i = 0; i < 8; ++i) acc[i] += s_h[i][k] * w;
    }
    #pragma unroll
    for (int i = 0; i < 8; ++i) {
        int n = n0 + i;
        out[n * IN_DIM + tx] = gmask[n] ? acc[i] : 0.f;
    }
    if (tx < 24) {
        int i = tx / 3, c = tx % 3;
        int n = n0 + i;
        out[NN * IN_DIM + n * 3 + c] = gmask[n] ? x[n * 3 + c] : 0.f;
    }
}

extern "C" void kernel_launch(void* const* d_in, const int* in_sizes, int n_in,
                              void* d_out, int out_size, void* d_ws, size_t ws_size,
                              hipStream_t stream) {
    const float* H_t   = (const float*)d_in[0];
    const float* X_t   = (const float*)d_in[1];
    const float* cond  = (const float*)d_in[2];
    const float* t_in  = (const float*)d_in[3];
    const int*   edges = (const int*)d_in[4];
    const int*   etype = (const int*)d_in[5];
    const int*   gmask = (const int*)d_in[6];
    const float* W0 = (const float*)d_in[8];
    const float* b0 = (const float*)d_in[9];
    const float* W1 = (const float*)d_in[10];
    const float* b1 = (const float*)d_in[11];
    const float* W2 = (const float*)d_in[12];
    const float* b2 = (const float*)d_in[13];
    const float* edge_table = (const float*)d_in[14];
    const float* We = (const float*)d_in[15];
    const float* be = (const float*)d_in[16];
    const float* Wx = (const float*)d_in[17];
    const float* bx = (const float*)d_in[18];
    const float* Wh = (const float*)d_in[19];
    const float* bh = (const float*)d_in[20];
    const float* h2i_W = (const float*)d_in[21];
    const float* h2i_b = (const float*)d_in[22];

    char* p = (char*)d_ws;
    float* h = (float*)p;           p += (size_t)NN * HID * 4;
    u16* h_bf = (u16*)p;            p += (size_t)NN * HID * 2;
    float* x = (float*)p;           p += (size_t)NN * 3 * 4;
    u16* Cbf = (u16*)p;             p += (size_t)NN * 256 * 2;
    float4* geom = (float4*)p;      p += (size_t)NE * 16;
    u16* Bpack = (u16*)p;           p += (size_t)PACK_TOT * 2;
    float* tv = (float*)p;          p += (size_t)768 * 4;
    float* wed2 = (float*)p;        p += (size_t)384 * 4;
    int* row_start = (int*)p;       p += (size_t)(NN + 4) * 4;
    int* deg = (int*)p;             p += (size_t)NN * 4;
    int* head = (int*)p;            p += (size_t)NN * 4;
    int* src_s = (int*)p;           p += (size_t)NE * 4;
    int* dst_s = (int*)p;           p += (size_t)NE * 4;
    int* et_s = (int*)p;            p += (size_t)NE * 4;
    size_t need = (size_t)(p - (char*)d_ws);

    if (ws_size >= need) {
        hipMemsetAsync(deg, 0, NN * sizeof(int), stream);
        hist_kernel<<<256, 256, 0, stream>>>(X_t, edges, x, deg);
        scan_kernel<<<1, 256, 0, stream>>>(deg, row_start, head);
        scatter_kernel<<<256, 256, 0, stream>>>(edges, etype, head, src_s, dst_s, et_s);
        pack_all_kernel<<<(PACK_TOT + 255) / 256, 256, 0, stream>>>(
            We, W0, W1, W2, Wh, h2i_W, Bpack);
        precomp_tv_kernel<<<5, 256, 0, stream>>>(edge_table, We, be, tv, wed2);
        node_mlp_mfma_kernel<<<NB64, 256, 0, stream>>>(
            H_t, cond, t_in,
            Bpack + OFF_W0, b0, Bpack + OFF_W1, b1, Bpack + OFF_W2, b2,
            h, h_bf);
        for (int l = 0; l < 3; ++l) {
            cvec_kernel<<<NB64, 256, 0, stream>>>(
                h_bf, Bpack + OFF_WE + (size_t)l * 40960, Cbf);
            geom_kernel<<<(NE + 255) / 256, 256, 0, stream>>>(x, src_s, dst_s, geom);
            node_fused_kernel<<<NN / NUB, 256, 0, stream>>>(
                h, h_bf, x, Cbf, geom, src_s, et_s, row_start,
                tv + (size_t)l * 256, wed2 + (size_t)l * 128,
                Wx + l * HID, bx + l,
                Bpack + OFF_WH + (size_t)l * 32768, bh + l * HID);
        }
        final_mfma_kernel<<<NB64, 256, 0, stream>>>(
            h_bf, x, gmask, Bpack + OFF_H2I, h2i_b, (float*)d_out);
    } else {
        // fallback: scalar atomic path (~21 MB)
        float* ws    = (float*)d_ws;
        float* fh    = ws;
        float* fx    = fh + NN * HID;
        float* cnt   = fx + NN * 3;
        float* fagg_m = cnt + NN;
        float* fagg_x = fagg_m + NN * HID;

        hipMemsetAsync(cnt, 0, NN * sizeof(float), stream);
        init_fb_kernel<<<256, 256, 0, stream>>>(X_t, edges, fx, cnt);
        node_mlp_kernel<<<NN / 16, 128, 0, stream>>>(H_t, cond, t_in,
                                                     W0, b0, W1, b1, W2, b2, fh);
        for (int l = 0; l < 3; ++l) {
            hipMemsetAsync(fagg_m, 0, (size_t)NN * 131 * sizeof(float), stream);
            edge_gemm_fb_kernel<<<NE / TILE_E, 256, 0, stream>>>(
                fh, fx, edges, etype, edge_table,
                We + (size_t)l * DE * HID, be + l * HID,
                Wx + l * HID, bx + l, fagg_m, fagg_x);
            node_update_fb_kernel<<<NN / 16, 128, 0, stream>>>(
                fh, fx, fagg_m, fagg_x, cnt,
                Wh + (size_t)l * 256 * HID, bh + l * HID);
        }
        final_fb_kernel<<<NN / 8, 64, 0, stream>>>(fh, fx, gmask, h2i_W, h2i_b, (float*)d_out);
    }
}

// Round 13
// 414.228 us; speedup vs baseline: 1.2499x; 1.0423x over previous
//
#include <hip/hip_runtime.h>
#include <math.h>

#define NN 20000
#define NE 256000
#define IN_DIM 64
#define HID 128
#define DE 289     // 2*HID + 1 + 32
#define D0 320     // IN_DIM + 2*HID
#define TILE_E 64
#define NB64 313   // ceil(NN/64)
#define NUB 16     // nodes per block (fused node kernel)

typedef unsigned short u16;
typedef unsigned int u32;
typedef unsigned long long u64;
typedef __attribute__((ext_vector_type(8))) short short8;
typedef __attribute__((ext_vector_type(4))) float float4v;

// Bpack layout offsets (u16 elements)
#define OFF_WE   0          // 3 x 40960 (K=289 pad 320, N=128) — tiles 0..3 = We rows 0..255
#define OFF_W0   122880     // 40960 (K=320, N=128)
#define OFF_W1   163840     // 16384 (K=128, N=128)
#define OFF_W2   180224     // 16384
#define OFF_WH   196608     // 3 x 32768 (K=256, N=128)
#define OFF_H2I  294912     // 8192 (K=128, N=64)
#define PACK_TOT 303104

static __device__ __forceinline__ u16 f2bf(float f) {
    unsigned int u = __float_as_uint(f);
    u += 0x7fffu + ((u >> 16) & 1u);
    return (u16)(u >> 16);
}
static __device__ __forceinline__ float bf2f(u16 s) {
    return __uint_as_float(((unsigned int)s) << 16);
}
static __device__ __forceinline__ float bflo(u32 u) { return bf2f((u16)(u & 0xffffu)); }
static __device__ __forceinline__ float bfhi(u32 u) { return bf2f((u16)(u >> 16)); }
static __device__ __forceinline__ uint4 pack8(const float* v) {
    uint4 r;
    r.x = (u32)f2bf(v[0]) | ((u32)f2bf(v[1]) << 16);
    r.y = (u32)f2bf(v[2]) | ((u32)f2bf(v[3]) << 16);
    r.z = (u32)f2bf(v[4]) | ((u32)f2bf(v[5]) << 16);
    r.w = (u32)f2bf(v[6]) | ((u32)f2bf(v[7]) << 16);
    return r;
}
static __device__ __forceinline__ void unpack8(uint4 a, float* o) {
    o[0]=bflo(a.x); o[1]=bfhi(a.x); o[2]=bflo(a.y); o[3]=bfhi(a.y);
    o[4]=bflo(a.z); o[5]=bfhi(a.z); o[6]=bflo(a.w); o[7]=bfhi(a.w);
}
static __device__ __forceinline__ float silu(float v) {
    return v * (1.f / (1.f + __expf(-v)));
}

// ================= CSR build =================
__global__ __launch_bounds__(256) void hist_kernel(
    const float* __restrict__ X_t, const int* __restrict__ edges,
    float* __restrict__ x, int* __restrict__ deg)
{
    int gid = blockIdx.x * blockDim.x + threadIdx.x;
    int stride = gridDim.x * blockDim.x;
    for (int i = gid; i < NN * 3; i += stride) x[i] = X_t[i];
    for (int e = gid; e < NE; e += stride)
        atomicAdd(&deg[edges[NE + e]], 1);
}

__global__ __launch_bounds__(256) void scan_kernel(
    const int* __restrict__ deg, int* __restrict__ row_start, int* __restrict__ head)
{
    __shared__ int s[256];
    int tx = threadIdx.x;
    const int per = (NN + 255) / 256;
    int st = tx * per, en = st + per;
    if (st > NN) st = NN;
    if (en > NN) en = NN;
    int sum = 0;
    for (int i = st; i < en; ++i) sum += deg[i];
    s[tx] = sum;
    __syncthreads();
    for (int off = 1; off < 256; off <<= 1) {
        int t = (tx >= off) ? s[tx - off] : 0;
        __syncthreads();
        s[tx] += t;
        __syncthreads();
    }
    int run = (tx == 0) ? 0 : s[tx - 1];
    for (int i = st; i < en; ++i) {
        row_start[i] = run; head[i] = run; run += deg[i];
    }
    if (tx == 255) row_start[NN] = run;
}

// permute edges into dst-sorted order
__global__ __launch_bounds__(256) void scatter_kernel(
    const int* __restrict__ edges, const int* __restrict__ etype,
    int* __restrict__ head,
    int* __restrict__ src_s, int* __restrict__ dst_s, int* __restrict__ et_s)
{
    int gid = blockIdx.x * blockDim.x + threadIdx.x;
    int stride = gridDim.x * blockDim.x;
    for (int e = gid; e < NE; e += stride) {
        int d = edges[NE + e];
        int p = atomicAdd(&head[d], 1);
        src_s[p] = edges[e];
        dst_s[p] = d;
        et_s[p] = etype[e];
    }
}

// ================= weight frag-order packing =================
__global__ __launch_bounds__(256) void pack_all_kernel(
    const float* __restrict__ We, const float* __restrict__ W0,
    const float* __restrict__ W1, const float* __restrict__ W2,
    const float* __restrict__ Wh, const float* __restrict__ h2i,
    u16* __restrict__ Bp)
{
    int idx = blockIdx.x * 256 + threadIdx.x;
    if (idx >= PACK_TOT) return;
    const float* src; int N = 128, Ksrc; int r;
    if (idx < OFF_W0) {
        int layer = idx / 40960; r = idx - layer * 40960;
        src = We + (size_t)layer * DE * HID; Ksrc = DE;
    } else if (idx < OFF_W1) { r = idx - OFF_W0; src = W0; Ksrc = 320; }
    else if (idx < OFF_W2)   { r = idx - OFF_W1; src = W1; Ksrc = 128; }
    else if (idx < OFF_WH)   { r = idx - OFF_W2; src = W2; Ksrc = 128; }
    else if (idx < OFF_H2I) {
        int t = idx - OFF_WH; int layer = t / 32768; r = t - layer * 32768;
        src = Wh + (size_t)layer * 256 * HID; Ksrc = 256;
    } else { r = idx - OFF_H2I; src = h2i; Ksrc = 128; N = 64; }
    int ntc = N / 16;
    int j = r & 7, lane = (r >> 3) & 63;
    int rem = r >> 9;
    int nt = rem % ntc, ks = rem / ntc;
    int k = ks * 32 + ((lane >> 4) << 3) + j;
    int c = nt * 16 + (lane & 15);
    Bp[idx] = f2bf((k < Ksrc) ? src[(size_t)k * N + c] : 0.f);
}

// ================= edge tail precompute (f32) =================
__global__ __launch_bounds__(256) void precomp_tv_kernel(
    const float* __restrict__ edge_table, const float* __restrict__ We,
    const float* __restrict__ be, float* __restrict__ tv, float* __restrict__ wed2)
{
    int idx = blockIdx.x * 256 + threadIdx.x;
    if (idx < 768) {
        int f = idx & 127, t = (idx >> 7) & 1, l = idx >> 8;
        float acc = be[l * 128 + f];
        const float* W = We + (size_t)l * DE * HID;
        #pragma unroll
        for (int k = 0; k < 32; ++k)
            acc += edge_table[t * 32 + k] * W[(size_t)(257 + k) * HID + f];
        tv[l * 256 + t * 128 + f] = acc;
    } else if (idx < 1152) {
        int r = idx - 768;
        int f = r & 127, l = r >> 7;
        wed2[l * 128 + f] = We[(size_t)l * DE * HID + (size_t)256 * HID + f];
    }
}

// ================= per-layer edge geometry: (dx,dy,dz,d2) =================
__global__ __launch_bounds__(256) void geom_kernel(
    const float* __restrict__ x,
    const int* __restrict__ src_s, const int* __restrict__ dst_s,
    float4* __restrict__ geom)
{
    int e = blockIdx.x * 256 + threadIdx.x;
    if (e >= NE) return;
    int s = src_s[e], d = dst_s[e];
    float dx = x[s*3+0]-x[d*3+0], dy = x[s*3+1]-x[d*3+1], dz = x[s*3+2]-x[d*3+2];
    geom[e] = make_float4(dx, dy, dz, dx*dx + dy*dy + dz*dz);
}

// ================= node MLP: MFMA, 64 nodes/block =================
__global__ __launch_bounds__(256) void node_mlp_mfma_kernel(
    const float* __restrict__ H_t, const float* __restrict__ cond,
    const float* __restrict__ t_in,
    const u16* __restrict__ W0p, const float* __restrict__ b0,
    const u16* __restrict__ W1p, const float* __restrict__ b1,
    const u16* __restrict__ W2p, const float* __restrict__ b2,
    float* __restrict__ h, u16* __restrict__ h_bf)
{
    __shared__ u16 s_A[64 * 64];
    __shared__ u16 s_B[64 * 128];
    __shared__ u16 s_h[64 * 128];
    __shared__ float s_t[64];

    int tx = threadIdx.x;
    int n0 = blockIdx.x * 64;
    int l = tx & 63, w = tx >> 6;
    int mt_base = (w & 1) * 2, nt_base = (w >> 1) * 4;
    const float cfr = -logf(10000.f) / 63.f;

    if (tx < 64) s_t[tx] = (n0 + tx < NN) ? t_in[n0 + tx] : 0.f;

    float4v acc[2][4];
    #pragma unroll
    for (int mi = 0; mi < 2; ++mi)
        #pragma unroll
        for (int ni = 0; ni < 4; ++ni) acc[mi][ni] = (float4v){0.f,0.f,0.f,0.f};

    for (int t = 0; t < 5; ++t) {
        __syncthreads();
        #pragma unroll
        for (int it = 0; it < 2; ++it) {
            int flat = it * 256 + tx;
            int n = flat >> 3, sl = flat & 7;
            int c = sl ^ (n & 7);
            int k0 = t * 64 + c * 8;
            float tv8[8];
            int gn = n0 + n;
            if (gn < NN) {
                if (k0 < 192) {
                    const float* src = (k0 < 64) ? &H_t[(size_t)gn * IN_DIM + k0]
                                                 : &cond[(size_t)gn * HID + (k0 - 64)];
                    float4 a = *(const float4*)src;
                    float4 b = *(const float4*)(src + 4);
                    tv8[0]=a.x; tv8[1]=a.y; tv8[2]=a.z; tv8[3]=a.w;
                    tv8[4]=b.x; tv8[5]=b.y; tv8[6]=b.z; tv8[7]=b.w;
                } else {
                    float tv = s_t[n];
                    int jj = (k0 - 192) & 63;
                    bool is_sin = (k0 < 256);
                    #pragma unroll
                    for (int jx = 0; jx < 8; ++jx) {
                        float ang = tv * __expf(cfr * (float)(jj + jx));
                        tv8[jx] = is_sin ? __sinf(ang) : __cosf(ang);
                    }
                }
            } else {
                #pragma unroll
                for (int jx = 0; jx < 8; ++jx) tv8[jx] = 0.f;
            }
            *(uint4*)&s_A[n * 64 + sl * 8] = pack8(tv8);
        }
        #pragma unroll
        for (int it = 0; it < 4; ++it) {
            int flat = it * 256 + tx;
            ((uint4*)s_B)[flat] = ((const uint4*)(W0p + (size_t)t * 8192))[flat];
        }
        __syncthreads();
        #pragma unroll
        for (int s = 0; s < 2; ++s) {
            short8 af[2], bfv[4];
            #pragma unroll
            for (int mi = 0; mi < 2; ++mi) {
                int m = (mt_base + mi) * 16 + (l & 15);
                int c = s * 4 + (l >> 4);
                int slot = c ^ (l & 7);
                af[mi] = *(const short8*)(s_A + m * 64 + slot * 8);
            }
            #pragma unroll
            for (int ni = 0; ni < 4; ++ni)
                bfv[ni] = *(const short8*)(s_B + ((s * 8 + nt_base + ni) * 64 + l) * 8);
            #pragma unroll
            for (int mi = 0; mi < 2; ++mi)
                #pragma unroll
                for (int ni = 0; ni < 4; ++ni)
                    acc[mi][ni] = __builtin_amdgcn_mfma_f32_16x16x32_bf16(
                        af[mi], bfv[ni], acc[mi][ni], 0, 0, 0);
        }
    }
    #pragma unroll
    for (int mi = 0; mi < 2; ++mi) {
        #pragma unroll
        for (int ni = 0; ni < 4; ++ni) {
            int f = (nt_base + ni) * 16 + (l & 15);
            float bv = b0[f];
            #pragma unroll
            for (int r = 0; r < 4; ++r) {
                int m = (mt_base + mi) * 16 + (l >> 4) * 4 + r;
                float v = fmaxf(acc[mi][ni][r] + bv, 0.f);
                int slot = (f >> 3) ^ (m & 7);
                s_h[m * 128 + slot * 8 + (f & 7)] = f2bf(v);
            }
            acc[mi][ni] = (float4v){0.f,0.f,0.f,0.f};
        }
    }
    for (int t = 0; t < 2; ++t) {
        __syncthreads();
        #pragma unroll
        for (int it = 0; it < 4; ++it) {
            int flat = it * 256 + tx;
            ((uint4*)s_B)[flat] = ((const uint4*)(W1p + (size_t)t * 8192))[flat];
        }
        __syncthreads();
        #pragma unroll
        for (int s = 0; s < 2; ++s) {
            short8 af[2], bfv[4];
            #pragma unroll
            for (int mi = 0; mi < 2; ++mi) {
                int m = (mt_base + mi) * 16 + (l & 15);
                int c = t * 8 + s * 4 + (l >> 4);
                int slot = c ^ (l & 7);
                af[mi] = *(const short8*)(s_h + m * 128 + slot * 8);
            }
            #pragma unroll
            for (int ni = 0; ni < 4; ++ni)
                bfv[ni] = *(const short8*)(s_B + ((s * 8 + nt_base + ni) * 64 + l) * 8);
            #pragma unroll
            for (int mi = 0; mi < 2; ++mi)
                #pragma unroll
                for (int ni = 0; ni < 4; ++ni)
                    acc[mi][ni] = __builtin_amdgcn_mfma_f32_16x16x32_bf16(
                        af[mi], bfv[ni], acc[mi][ni], 0, 0, 0);
        }
    }
    __syncthreads();
    #pragma unroll
    for (int mi = 0; mi < 2; ++mi) {
        #pragma unroll
        for (int ni = 0; ni < 4; ++ni) {
            int f = (nt_base + ni) * 16 + (l & 15);
            float bv = b1[f];
            #pragma unroll
            for (int r = 0; r < 4; ++r) {
                int m = (mt_base + mi) * 16 + (l >> 4) * 4 + r;
                float v = fmaxf(acc[mi][ni][r] + bv, 0.f);
                int slot = (f >> 3) ^ (m & 7);
                s_h[m * 128 + slot * 8 + (f & 7)] = f2bf(v);
            }
            acc[mi][ni] = (float4v){0.f,0.f,0.f,0.f};
        }
    }
    for (int t = 0; t < 2; ++t) {
        __syncthreads();
        #pragma unroll
        for (int it = 0; it < 4; ++it) {
            int flat = it * 256 + tx;
            ((uint4*)s_B)[flat] = ((const uint4*)(W2p + (size_t)t * 8192))[flat];
        }
        __syncthreads();
        #pragma unroll
        for (int s = 0; s < 2; ++s) {
            short8 af[2], bfv[4];
            #pragma unroll
            for (int mi = 0; mi < 2; ++mi) {
                int m = (mt_base + mi) * 16 + (l & 15);
                int c = t * 8 + s * 4 + (l >> 4);
                int slot = c ^ (l & 7);
                af[mi] = *(const short8*)(s_h + m * 128 + slot * 8);
            }
            #pragma unroll
            for (int ni = 0; ni < 4; ++ni)
                bfv[ni] = *(const short8*)(s_B + ((s * 8 + nt_base + ni) * 64 + l) * 8);
            #pragma unroll
            for (int mi = 0; mi < 2; ++mi)
                #pragma unroll
                for (int ni = 0; ni < 4; ++ni)
                    acc[mi][ni] = __builtin_amdgcn_mfma_f32_16x16x32_bf16(
                        af[mi], bfv[ni], acc[mi][ni], 0, 0, 0);
        }
    }
    #pragma unroll
    for (int mi = 0; mi < 2; ++mi) {
        #pragma unroll
        for (int ni = 0; ni < 4; ++ni) {
            int f = (nt_base + ni) * 16 + (l & 15);
            float bv = b2[f];
            #pragma unroll
            for (int r = 0; r < 4; ++r) {
                int m = (mt_base + mi) * 16 + (l >> 4) * 4 + r;
                int gn = n0 + m;
                if (gn < NN) {
                    float v = acc[mi][ni][r] + bv;
                    h[(size_t)gn * HID + f] = v;
                    h_bf[(size_t)gn * HID + f] = f2bf(v);
                }
            }
        }
    }
}

// ================= cvec: C[n][0:128]=h@We_src, C[n][128:256]=h@We_dst (bf16 out) =================
__global__ __launch_bounds__(256) void cvec_kernel(
    const u16* __restrict__ h_bf, const u16* __restrict__ WEp,
    u16* __restrict__ Cbf)
{
    __shared__ u16 s_A[64 * 64];
    __shared__ u16 s_B[64 * 128];

    int tx = threadIdx.x;
    int n0 = blockIdx.x * 64;
    int l = tx & 63, w = tx >> 6;
    int mt_base = (w & 1) * 2, nt_base = (w >> 1) * 4;

    float4v acc[2][2][4];  // [side][mi][ni]
    #pragma unroll
    for (int sd = 0; sd < 2; ++sd)
        #pragma unroll
        for (int mi = 0; mi < 2; ++mi)
            #pragma unroll
            for (int ni = 0; ni < 4; ++ni)
                acc[sd][mi][ni] = (float4v){0.f,0.f,0.f,0.f};

    for (int t = 0; t < 4; ++t) {
        __syncthreads();
        #pragma unroll
        for (int it = 0; it < 2; ++it) {
            int flat = it * 256 + tx;
            int n = flat >> 3, sl = flat & 7;
            int c = sl ^ (n & 7);
            int gn = n0 + n;
            uint4 v = make_uint4(0,0,0,0);
            if (gn < NN) v = *(const uint4*)(h_bf + (size_t)gn * 128 + (t & 1) * 64 + c * 8);
            *(uint4*)&s_A[n * 64 + sl * 8] = v;
        }
        #pragma unroll
        for (int it = 0; it < 4; ++it) {
            int flat = it * 256 + tx;
            ((uint4*)s_B)[flat] = ((const uint4*)(WEp + (size_t)t * 8192))[flat];
        }
        __syncthreads();
        int sd = t >> 1;
        #pragma unroll
        for (int s = 0; s < 2; ++s) {
            short8 af[2], bfv[4];
            #pragma unroll
            for (int mi = 0; mi < 2; ++mi) {
                int m = (mt_base + mi) * 16 + (l & 15);
                int c = s * 4 + (l >> 4);
                int slot = c ^ (l & 7);
                af[mi] = *(const short8*)(s_A + m * 64 + slot * 8);
            }
            #pragma unroll
            for (int ni = 0; ni < 4; ++ni)
                bfv[ni] = *(const short8*)(s_B + ((s * 8 + nt_base + ni) * 64 + l) * 8);
            #pragma unroll
            for (int mi = 0; mi < 2; ++mi)
                #pragma unroll
                for (int ni = 0; ni < 4; ++ni)
                    acc[sd][mi][ni] = __builtin_amdgcn_mfma_f32_16x16x32_bf16(
                        af[mi], bfv[ni], acc[sd][mi][ni], 0, 0, 0);
        }
    }
    #pragma unroll
    for (int sd = 0; sd < 2; ++sd) {
        #pragma unroll
        for (int mi = 0; mi < 2; ++mi) {
            #pragma unroll
            for (int ni = 0; ni < 4; ++ni) {
                int f = sd * 128 + (nt_base + ni) * 16 + (l & 15);
                #pragma unroll
                for (int r = 0; r < 4; ++r) {
                    int m = (mt_base + mi) * 16 + (l >> 4) * 4 + r;
                    int gn = n0 + m;
                    if (gn < NN)
                        Cbf[(size_t)gn * 256 + f] = f2bf(acc[sd][mi][ni][r]);
                }
            }
        }
    }
}

// ================= fused node update v2: 512 thr, 2-way edge parallel + prefetch =================
// thread: node i = tx>>5, edge-parity q = (tx>>4)&1, feat-chunk p = tx&15 (8 feats)
__global__ __launch_bounds__(512) void node_fused_kernel(
    float* __restrict__ h, u16* __restrict__ h_bf, float* __restrict__ x,
    const u16* __restrict__ Cbf, const float4* __restrict__ geom,
    const int* __restrict__ src_s, const int* __restrict__ et_s,
    const int* __restrict__ row_start,
    const float* __restrict__ tv_l, const float* __restrict__ wed2_l,
    const float* __restrict__ Wx_l, const float* __restrict__ bx_l,
    const u16* __restrict__ Whp_l, const float* __restrict__ bh_l)
{
    __shared__ u16 s_A[NUB * 256];   // 8 KB: [node][256k] xor-swizzled: h | agg
    __shared__ u16 s_B[64 * 128];    // 16 KB
    __shared__ int s_rs[NUB + 1];

    int tx = threadIdx.x;
    int n0 = blockIdx.x * NUB;
    int l = tx & 63, w = tx >> 6;    // 8 waves

    if (tx < NUB + 1) s_rs[tx] = row_start[n0 + tx];
    // stage h_bf (chunks 0..15)
    if (tx < 256) {
        int n = tx >> 4, c = tx & 15;
        int slot = c ^ (n & 7);
        uint4 v = *(const uint4*)(h_bf + (size_t)(n0 + n) * 128 + c * 8);
        *(uint4*)&s_A[n * 256 + slot * 8] = v;
    }
    __syncthreads();
    // fused message + aggregation (2 parities per node)
    {
        int i = tx >> 5, q = (tx >> 4) & 1, p = tx & 15;
        int gn = n0 + i;
        int rs = s_rs[i], re = s_rs[i + 1];
        float cdv[8], tv0[8], tv1[8], wed[8], wx[8];
        unpack8(*(const uint4*)(Cbf + (size_t)gn * 256 + 128 + p * 8), cdv);
        #pragma unroll
        for (int qq = 0; qq < 2; ++qq) {
            float4 a0 = *(const float4*)(tv_l + p * 8 + qq * 4);
            float4 a1 = *(const float4*)(tv_l + 128 + p * 8 + qq * 4);
            float4 a2 = *(const float4*)(wed2_l + p * 8 + qq * 4);
            float4 a3 = *(const float4*)(Wx_l + p * 8 + qq * 4);
            tv0[qq*4+0]=a0.x; tv0[qq*4+1]=a0.y; tv0[qq*4+2]=a0.z; tv0[qq*4+3]=a0.w;
            tv1[qq*4+0]=a1.x; tv1[qq*4+1]=a1.y; tv1[qq*4+2]=a1.z; tv1[qq*4+3]=a1.w;
            wed[qq*4+0]=a2.x; wed[qq*4+1]=a2.y; wed[qq*4+2]=a2.z; wed[qq*4+3]=a2.w;
            wx[qq*4+0]=a3.x; wx[qq*4+1]=a3.y; wx[qq*4+2]=a3.z; wx[qq*4+3]=a3.w;
        }
        float bxv = bx_l[0];
        float ag[8];
        #pragma unroll
        for (int f = 0; f < 8; ++f) ag[f] = 0.f;
        float sxx = 0.f;

        int j = rs + q;
        if (j < re) {
            int et = et_s[j];
            float4 g = geom[j];
            int sj = src_s[j];
            uint4 craw = *(const uint4*)(Cbf + (size_t)sj * 256 + p * 8);
            while (1) {
                int jn = j + 2;
                bool more = (jn < re);
                int et2 = 0; float4 g2 = g; uint4 craw2 = craw;
                if (more) {
                    et2 = et_s[jn];
                    g2 = geom[jn];
                    int sj2 = src_s[jn];
                    craw2 = *(const uint4*)(Cbf + (size_t)sj2 * 256 + p * 8);
                }
                float av[8];
                unpack8(craw, av);
                float wpart = 0.f;
                #pragma unroll
                for (int f = 0; f < 8; ++f) {
                    float tvf = et ? tv1[f] : tv0[f];
                    float v = av[f] + cdv[f] + tvf + g.w * wed[f];
                    float m = silu(v);
                    ag[f] += m;
                    wpart += m * wx[f];
                }
                wpart += __shfl_xor(wpart, 1);
                wpart += __shfl_xor(wpart, 2);
                wpart += __shfl_xor(wpart, 4);
                wpart += __shfl_xor(wpart, 8);
                if (p < 3) {
                    float gc = (p == 0) ? g.x : ((p == 1) ? g.y : g.z);
                    sxx += gc * (wpart + bxv);
                }
                if (!more) break;
                j = jn; et = et2; g = g2; craw = craw2;
            }
        }
        // combine parities (lane XOR 16 stays within this node's 32-lane group)
        #pragma unroll
        for (int f = 0; f < 8; ++f) ag[f] += __shfl_xor(ag[f], 16);
        sxx += __shfl_xor(sxx, 16);
        if (q == 0) {
            int c2 = 16 + p;
            int slot = c2 ^ (i & 7);
            *(uint4*)&s_A[i * 256 + slot * 8] = pack8(ag);
            if (p < 3)
                x[gn * 3 + p] += sxx / ((float)(re - rs) + 1.f);
        }
    }

    // Wh GEMM: 8 waves, wave w covers N-tile w (16 feats)
    float4v acc = (float4v){0.f, 0.f, 0.f, 0.f};
    for (int t = 0; t < 4; ++t) {
        __syncthreads();
        #pragma unroll
        for (int it = 0; it < 2; ++it) {
            int flat = it * 512 + tx;
            ((uint4*)s_B)[flat] = ((const uint4*)(Whp_l + (size_t)t * 8192))[flat];
        }
        __syncthreads();
        #pragma unroll
        for (int s = 0; s < 2; ++s) {
            short8 af, bfv;
            {
                int m = l & 15;
                int c = t * 8 + s * 4 + (l >> 4);
                int slot = c ^ (l & 7);
                af = *(const short8*)(s_A + m * 256 + slot * 8);
            }
            bfv = *(const short8*)(s_B + ((s * 8 + w) * 64 + l) * 8);
            acc = __builtin_amdgcn_mfma_f32_16x16x32_bf16(af, bfv, acc, 0, 0, 0);
        }
    }
    // epilogue: h += silu(acc + bh)
    {
        int f = w * 16 + (l & 15);
        float bv = bh_l[f];
        #pragma unroll
        for (int r = 0; r < 4; ++r) {
            int m = (l >> 4) * 4 + r;
            int gn = n0 + m;
            float v = acc[r] + bv;
            float hn = h[(size_t)gn * HID + f] + silu(v);
            h[(size_t)gn * HID + f] = hn;
            h_bf[(size_t)gn * HID + f] = f2bf(hn);
        }
    }
}

// ================= final: MFMA h2i, 64 nodes/block =================
__global__ __launch_bounds__(256) void final_mfma_kernel(
    const u16* __restrict__ h_bf, const float* __restrict__ x,
    const int* __restrict__ gmask,
    const u16* __restrict__ h2ip, const float* __restrict__ b,
    float* __restrict__ out)
{
    __shared__ u16 s_A[64 * 128];
    __shared__ u16 s_B[4096];

    int tx = threadIdx.x;
    int n0 = blockIdx.x * 64;
    int l = tx & 63, w = tx >> 6;
    int mt_base = (w & 1) * 2, nt_base = (w >> 1) * 2;

    #pragma unroll
    for (int it = 0; it < 4; ++it) {
        int flat = it * 256 + tx;
        int n = flat >> 4, c = flat & 15;
        int slot = c ^ (n & 7);
        int gn = n0 + n;
        uint4 v = make_uint4(0,0,0,0);
        if (gn < NN) v = *(const uint4*)(h_bf + (size_t)gn * 128 + c * 8);
        *(uint4*)&s_A[n * 128 + slot * 8] = v;
    }

    float4v acc[2][2];
    #pragma unroll
    for (int mi = 0; mi < 2; ++mi)
        #pragma unroll
        for (int ni = 0; ni < 2; ++ni) acc[mi][ni] = (float4v){0.f,0.f,0.f,0.f};

    for (int t = 0; t < 2; ++t) {
        __syncthreads();
        #pragma unroll
        for (int it = 0; it < 2; ++it) {
            int flat = it * 256 + tx;
            ((uint4*)s_B)[flat] = ((const uint4*)(h2ip + (size_t)t * 4096))[flat];
        }
        __syncthreads();
        #pragma unroll
        for (int s = 0; s < 2; ++s) {
            short8 af[2], bfv[2];
            #pragma unroll
            for (int mi = 0; mi < 2; ++mi) {
                int m = (mt_base + mi) * 16 + (l & 15);
                int c = t * 8 + s * 4 + (l >> 4);
                int slot = c ^ (l & 7);
                af[mi] = *(const short8*)(s_A + m * 128 + slot * 8);
            }
            #pragma unroll
            for (int ni = 0; ni < 2; ++ni)
                bfv[ni] = *(const short8*)(s_B + ((s * 4 + nt_base + ni) * 64 + l) * 8);
            #pragma unroll
            for (int mi = 0; mi < 2; ++mi)
                #pragma unroll
                for (int ni = 0; ni < 2; ++ni)
                    acc[mi][ni] = __builtin_amdgcn_mfma_f32_16x16x32_bf16(
                        af[mi], bfv[ni], acc[mi][ni], 0, 0, 0);
        }
    }
    #pragma unroll
    for (int mi = 0; mi < 2; ++mi) {
        #pragma unroll
        for (int ni = 0; ni < 2; ++ni) {
            int f = (nt_base + ni) * 16 + (l & 15);
            float bv = b[f];
            #pragma unroll
            for (int r = 0; r < 4; ++r) {
                int m = (mt_base + mi) * 16 + (l >> 4) * 4 + r;
                int gn = n0 + m;
                if (gn < NN)
                    out[(size_t)gn * IN_DIM + f] = gmask[gn] ? (acc[mi][ni][r] + bv) : 0.f;
            }
        }
    }
    if (tx < 192) {
        int i = tx / 3, c = tx % 3;
        int gn = n0 + i;
        if (gn < NN)
            out[(size_t)NN * IN_DIM + gn * 3 + c] = gmask[gn] ? x[gn * 3 + c] : 0.f;
    }
}

// ================= fallback path (atomic, scalar; used only if ws too small) =================
__global__ __launch_bounds__(256) void init_fb_kernel(
    const float* __restrict__ X_t, const int* __restrict__ edges,
    float* __restrict__ x, float* __restrict__ cnt)
{
    int gid = blockIdx.x * blockDim.x + threadIdx.x;
    int stride = gridDim.x * blockDim.x;
    for (int i = gid; i < NN * 3; i += stride) x[i] = X_t[i];
    for (int e = gid; e < NE; e += stride)
        atomicAdd(&cnt[edges[NE + e]], 1.0f);
}

__global__ __launch_bounds__(128) void node_mlp_kernel(
    const float* __restrict__ H_t, const float* __restrict__ cond,
    const float* __restrict__ t_in,
    const float* __restrict__ W0, const float* __restrict__ b0,
    const float* __restrict__ W1, const float* __restrict__ b1,
    const float* __restrict__ W2, const float* __restrict__ b2,
    float* __restrict__ h)
{
    __shared__ float s_feat[D0][20];
    __shared__ float s_h0[HID][20];
    __shared__ float s_h1[HID][20];
    int n0 = blockIdx.x * 16;
    int tx = threadIdx.x;

    for (int idx = tx; idx < 16 * IN_DIM; idx += 128) {
        int i = idx >> 6, k = idx & 63;
        s_feat[k][i] = H_t[(n0 + i) * IN_DIM + k];
    }
    for (int idx = tx; idx < 16 * HID; idx += 128) {
        int i = idx >> 7, k = idx & 127;
        s_feat[IN_DIM + k][i] = cond[(n0 + i) * HID + k];
    }
    const float cfr = -logf(10000.f) / 63.f;
    for (int idx = tx; idx < 16 * HID; idx += 128) {
        int i = idx >> 7, k = idx & 127;
        float tv = t_in[n0 + i];
        int jj = k & 63;
        float ang = tv * __expf(cfr * (float)jj);
        s_feat[IN_DIM + HID + k][i] = (k < 64) ? __sinf(ang) : __cosf(ang);
    }
    __syncthreads();

    float acc[16];
    {
        float bv = b0[tx];
        #pragma unroll
        for (int i = 0; i < 16; ++i) acc[i] = bv;
        for (int k = 0; k < D0; ++k) {
            float w = W0[k * HID + tx];
            float4 f0 = *(const float4*)&s_feat[k][0];
            float4 f1 = *(const float4*)&s_feat[k][4];
            float4 f2 = *(const float4*)&s_feat[k][8];
            float4 f3 = *(const float4*)&s_feat[k][12];
            acc[0] += f0.x*w; acc[1] += f0.y*w; acc[2] += f0.z*w; acc[3] += f0.w*w;
            acc[4] += f1.x*w; acc[5] += f1.y*w; acc[6] += f1.z*w; acc[7] += f1.w*w;
            acc[8] += f2.x*w; acc[9] += f2.y*w; acc[10]+= f2.z*w; acc[11]+= f2.w*w;
            acc[12]+= f3.x*w; acc[13]+= f3.y*w; acc[14]+= f3.z*w; acc[15]+= f3.w*w;
        }
        #pragma unroll
        for (int i = 0; i < 16; ++i) s_h0[tx][i] = fmaxf(acc[i], 0.f);
    }
    __syncthreads();
    {
        float bv = b1[tx];
        #pragma unroll
        for (int i = 0; i < 16; ++i) acc[i] = bv;
        for (int k = 0; k < HID; ++k) {
            float w = W1[k * HID + tx];
            float4 f0 = *(const float4*)&s_h0[k][0];
            float4 f1 = *(const float4*)&s_h0[k][4];
            float4 f2 = *(const float4*)&s_h0[k][8];
            float4 f3 = *(const float4*)&s_h0[k][12];
            acc[0] += f0.x*w; acc[1] += f0.y*w; acc[2] += f0.z*w; acc[3] += f0.w*w;
            acc[4] += f1.x*w; acc[5] += f1.y*w; acc[6] += f1.z*w; acc[7] += f1.w*w;
            acc[8] += f2.x*w; acc[9] += f2.y*w; acc[10]+= f2.z*w; acc[11]+= f2.w*w;
            acc[12]+= f3.x*w; acc[13]+= f3.y*w; acc[14]+= f3.z*w; acc[15]+= f3.w*w;
        }
        #pragma unroll
        for (int i = 0; i < 16; ++i) s_h1[tx][i] = fmaxf(acc[i], 0.f);
    }
    __syncthreads();
    {
        float bv = b2[tx];
        #pragma unroll
        for (int i = 0; i < 16; ++i) acc[i] = bv;
        for (int k = 0; k < HID; ++k) {
            float w = W2[k * HID + tx];
            float4 f0 = *(const float4*)&s_h1[k][0];
            float4 f1 = *(const float4*)&s_h1[k][4];
            float4 f2 = *(const float4*)&s_h1[k][8];
            float4 f3 = *(const float4*)&s_h1[k][12];
            acc[0] += f0.x*w; acc[1] += f0.y*w; acc[2] += f0.z*w; acc[3] += f0.w*w;
            acc[4] += f1.x*w; acc[5] += f1.y*w; acc[6] += f1.z*w; acc[7] += f1.w*w;
            acc[8] += f2.x*w; acc[9] += f2.y*w; acc[10]+= f2.z*w; acc[11]+= f2.w*w;
            acc[12]+= f3.x*w; acc[13]+= f3.y*w; acc[14]+= f3.z*w; acc[15]+= f3.w*w;
        }
        #pragma unroll
        for (int i = 0; i < 16; ++i) h[(n0 + i) * HID + tx] = acc[i];
    }
}

__global__ __launch_bounds__(256) void edge_gemm_fb_kernel(
    const float* __restrict__ h, const float* __restrict__ x,
    const int* __restrict__ edges, const int* __restrict__ etype,
    const float* __restrict__ edge_table,
    const float* __restrict__ We_l, const float* __restrict__ be_l,
    const float* __restrict__ Wx_l, const float* __restrict__ bx_l,
    float* __restrict__ agg_m, float* __restrict__ agg_x)
{
    __shared__ int s_src[TILE_E], s_dst[TILE_E];
    __shared__ float s_diff[TILE_E][3];
    __shared__ float s_tail[TILE_E][36];
    __shared__ float s_Af[TILE_E][36];
    __shared__ float s_Bf[33][HID];
    __shared__ float s_wx[HID];

    int e0 = blockIdx.x * TILE_E;
    int tx = threadIdx.x;
    int tf = tx & 15;
    int te = tx >> 4;

    if (tx < TILE_E) {
        int s = edges[e0 + tx];
        int d = edges[NE + e0 + tx];
        s_src[tx] = s; s_dst[tx] = d;
        float dx = x[s * 3 + 0] - x[d * 3 + 0];
        float dy = x[s * 3 + 1] - x[d * 3 + 1];
        float dz = x[s * 3 + 2] - x[d * 3 + 2];
        s_diff[tx][0] = dx; s_diff[tx][1] = dy; s_diff[tx][2] = dz;
        s_tail[tx][0] = dx * dx + dy * dy + dz * dz;
        int et = etype[e0 + tx];
        #pragma unroll
        for (int j = 0; j < 32; ++j) s_tail[tx][1 + j] = edge_table[et * 32 + j];
    }
    if (tx < HID) s_wx[tx] = Wx_l[tx];
    __syncthreads();

    float acc[4][8];
    #pragma unroll
    for (int i = 0; i < 4; ++i)
        #pragma unroll
        for (int j = 0; j < 8; ++j) acc[i][j] = 0.f;

    for (int t = 0; t < 9; ++t) {
        int k0 = t * 32;
        int klen = (t == 8) ? 33 : 32;
        __syncthreads();
        if (t < 8) {
            const bool use_src = (t < 4);
            int kbase = (t & 3) * 32;
            for (int q4 = tx; q4 < TILE_E * 8; q4 += 256) {
                int e = q4 >> 3, q = q4 & 7;
                int row = use_src ? s_src[e] : s_dst[e];
                float4 v = *(const float4*)&h[row * HID + kbase + q * 4];
                *(float4*)&s_Af[e][q * 4] = v;
            }
        }
        for (int q4 = tx; q4 < klen * 32; q4 += 256) {
            int kk = q4 >> 5, c4 = q4 & 31;
            float4 v = *(const float4*)&We_l[(k0 + kk) * HID + c4 * 4];
            *(float4*)&s_Bf[kk][c4 * 4] = v;
        }
        __syncthreads();
        const float (*Asrc)[36] = (t == 8) ? (const float (*)[36])s_tail
                                           : (const float (*)[36])s_Af;
        for (int kk = 0; kk < klen; ++kk) {
            float a0 = Asrc[te * 4 + 0][kk];
            float a1 = Asrc[te * 4 + 1][kk];
            float a2 = Asrc[te * 4 + 2][kk];
            float a3 = Asrc[te * 4 + 3][kk];
            float4 bv0 = *(const float4*)&s_Bf[kk][tf * 8];
            float4 bv1 = *(const float4*)&s_Bf[kk][tf * 8 + 4];
            float b[8] = {bv0.x, bv0.y, bv0.z, bv0.w, bv1.x, bv1.y, bv1.z, bv1.w};
            #pragma unroll
            for (int j = 0; j < 8; ++j) {
                acc[0][j] += a0 * b[j];
                acc[1][j] += a1 * b[j];
                acc[2][j] += a2 * b[j];
                acc[3][j] += a3 * b[j];
            }
        }
    }

    float wsum[4];
    #pragma unroll
    for (int i = 0; i < 4; ++i) {
        float p = 0.f;
        #pragma unroll
        for (int j = 0; j < 8; ++j) {
            int f = tf * 8 + j;
            float v = acc[i][j] + be_l[f];
            float m = silu(v);
            acc[i][j] = m;
            p += m * s_wx[f];
        }
        wsum[i] = p;
    }
    #pragma unroll
    for (int off = 1; off < 16; off <<= 1) {
        #pragma unroll
        for (int i = 0; i < 4; ++i) wsum[i] += __shfl_xor(wsum[i], off);
    }
    float bxv = bx_l[0];
    if (tf < 3) {
        #pragma unroll
        for (int i = 0; i < 4; ++i) {
            int e = te * 4 + i;
            float w2 = wsum[i] + bxv;
            atomicAdd(&agg_x[s_dst[e] * 3 + tf], s_diff[e][tf] * w2);
        }
    }
    #pragma unroll
    for (int i = 0; i < 4; ++i) {
        int d = s_dst[te * 4 + i];
        #pragma unroll
        for (int j = 0; j < 8; ++j)
            atomicAdd(&agg_m[d * HID + tf * 8 + j], acc[i][j]);
    }
}

__global__ __launch_bounds__(128) void node_update_fb_kernel(
    float* __restrict__ h, float* __restrict__ x,
    const float* __restrict__ agg_m, const float* __restrict__ agg_x,
    const float* __restrict__ cnt,
    const float* __restrict__ Wh_l, const float* __restrict__ bh_l)
{
    __shared__ float s_in[256][20];
    int n0 = blockIdx.x * 16;
    int tx = threadIdx.x;
    for (int idx = tx; idx < 16 * HID; idx += 128) {
        int i = idx >> 7, k = idx & 127;
        s_in[k][i] = h[(n0 + i) * HID + k];
    }
    for (int idx = tx; idx < 16 * HID; idx += 128) {
        int i = idx >> 7, k = idx & 127;
        s_in[HID + k][i] = agg_m[(n0 + i) * HID + k];
    }
    __syncthreads();
    float acc[16];
    float bv = bh_l[tx];
    #pragma unroll
    for (int i = 0; i < 16; ++i) acc[i] = bv;
    for (int k = 0; k < 256; ++k) {
        float w = Wh_l[k * HID + tx];
        float4 f0 = *(const float4*)&s_in[k][0];
        float4 f1 = *(const float4*)&s_in[k][4];
        float4 f2 = *(const float4*)&s_in[k][8];
        float4 f3 = *(const float4*)&s_in[k][12];
        acc[0] += f0.x*w; acc[1] += f0.y*w; acc[2] += f0.z*w; acc[3] += f0.w*w;
        acc[4] += f1.x*w; acc[5] += f1.y*w; acc[6] += f1.z*w; acc[7] += f1.w*w;
        acc[8] += f2.x*w; acc[9] += f2.y*w; acc[10]+= f2.z*w; acc[11]+= f2.w*w;
        acc[12]+= f3.x*w; acc[13]+= f3.y*w; acc[14]+= f3.z*w; acc[15]+= f3.w*w;
    }
    #pragma unroll
    for (int i = 0; i < 16; ++i) {
        float v = acc[i];
        h[(n0 + i) * HID + tx] = s_in[tx][i] + silu(v);
    }
    if (tx < 48) {
        int i = tx / 3, c = tx % 3;
        int n = n0 + i;
        x[n * 3 + c] += agg_x[n * 3 + c] / (cnt[n] + 1.f);
    }
}

__global__ __launch_bounds__(64) void final_fb_kernel(
    const float* __restrict__ h, const float* __restrict__ x,
    const int* __restrict__ gmask,
    const float* __restrict__ W, const float* __restrict__ b,
    float* __restrict__ out)
{
    __shared__ float s_h[8][HID];
    int n0 = blockIdx.x * 8;
    int tx = threadIdx.x;
    for (int idx = tx; idx < 8 * HID; idx += 64) {
        int i = idx >> 7, k = idx & 127;
        s_h[i][k] = h[(n0 + i) * HID + k];
    }
    __syncthreads();
    float acc[8];
    float bv = b[tx];
    #pragma unroll
    for (int i = 0; i < 8; ++i) acc[i] = bv;
    for (int k = 0; k < HID; ++k) {
        float w = W[k * IN_DIM + tx];
        #pragma unroll
        for (int i = 0; i < 8; ++i) acc[i] += s_h[i][k] * w;
    }
    #pragma unroll
    for (int i = 0; i < 8; ++i) {
        int n = n0 + i;
        out[n * IN_DIM + tx] = gmask[n] ? acc[i] : 0.f;
    }
    if (tx < 24) {
        int i = tx / 3, c = tx % 3;
        int n = n0 + i;
        out[NN * IN_DIM + n * 3 + c] = gmask[n] ? x[n * 3 + c] : 0.f;
    }
}

extern "C" void kernel_launch(void* const* d_in, const int* in_sizes, int n_in,
                              void* d_out, int out_size, void* d_ws, size_t ws_size,
                              hipStream_t stream) {
    const float* H_t   = (const float*)d_in[0];
    const float* X_t   = (const float*)d_in[1];
    const float* cond  = (const float*)d_in[2];
    const float* t_in  = (const float*)d_in[3];
    const int*   edges = (const int*)d_in[4];
    const int*   etype = (const int*)d_in[5];
    const int*   gmask = (const int*)d_in[6];
    const float* W0 = (const float*)d_in[8];
    const float* b0 = (const float*)d_in[9];
    const float* W1 = (const float*)d_in[10];
    const float* b1 = (const float*)d_in[11];
    const float* W2 = (const float*)d_in[12];
    const float* b2 = (const float*)d_in[13];
    const float* edge_table = (const float*)d_in[14];
    const float* We = (const float*)d_in[15];
    const float* be = (const float*)d_in[16];
    const float* Wx = (const float*)d_in[17];
    const float* bx = (const float*)d_in[18];
    const float* Wh = (const float*)d_in[19];
    const float* bh = (const float*)d_in[20];
    const float* h2i_W = (const float*)d_in[21];
    const float* h2i_b = (const float*)d_in[22];

    char* p = (char*)d_ws;
    float* h = (float*)p;           p += (size_t)NN * HID * 4;
    u16* h_bf = (u16*)p;            p += (size_t)NN * HID * 2;
    float* x = (float*)p;           p += (size_t)NN * 3 * 4;
    u16* Cbf = (u16*)p;             p += (size_t)NN * 256 * 2;
    float4* geom = (float4*)p;      p += (size_t)NE * 16;
    u16* Bpack = (u16*)p;           p += (size_t)PACK_TOT * 2;
    float* tv = (float*)p;          p += (size_t)768 * 4;
    float* wed2 = (float*)p;        p += (size_t)384 * 4;
    int* row_start = (int*)p;       p += (size_t)(NN + 4) * 4;
    int* deg = (int*)p;             p += (size_t)NN * 4;
    int* head = (int*)p;            p += (size_t)NN * 4;
    int* src_s = (int*)p;           p += (size_t)NE * 4;
    int* dst_s = (int*)p;           p += (size_t)NE * 4;
    int* et_s = (int*)p;            p += (size_t)NE * 4;
    size_t need = (size_t)(p - (char*)d_ws);

    if (ws_size >= need) {
        hipMemsetAsync(deg, 0, NN * sizeof(int), stream);
        hist_kernel<<<256, 256, 0, stream>>>(X_t, edges, x, deg);
        scan_kernel<<<1, 256, 0, stream>>>(deg, row_start, head);
        scatter_kernel<<<256, 256, 0, stream>>>(edges, etype, head, src_s, dst_s, et_s);
        pack_all_kernel<<<(PACK_TOT + 255) / 256, 256, 0, stream>>>(
            We, W0, W1, W2, Wh, h2i_W, Bpack);
        precomp_tv_kernel<<<5, 256, 0, stream>>>(edge_table, We, be, tv, wed2);
        node_mlp_mfma_kernel<<<NB64, 256, 0, stream>>>(
            H_t, cond, t_in,
            Bpack + OFF_W0, b0, Bpack + OFF_W1, b1, Bpack + OFF_W2, b2,
            h, h_bf);
        for (int l = 0; l < 3; ++l) {
            cvec_kernel<<<NB64, 256, 0, stream>>>(
                h_bf, Bpack + OFF_WE + (size_t)l * 40960, Cbf);
            geom_kernel<<<(NE + 255) / 256, 256, 0, stream>>>(x, src_s, dst_s, geom);
            node_fused_kernel<<<NN / NUB, 512, 0, stream>>>(
                h, h_bf, x, Cbf, geom, src_s, et_s, row_start,
                tv + (size_t)l * 256, wed2 + (size_t)l * 128,
                Wx + l * HID, bx + l,
                Bpack + OFF_WH + (size_t)l * 32768, bh + l * HID);
        }
        final_mfma_kernel<<<NB64, 256, 0, stream>>>(
            h_bf, x, gmask, Bpack + OFF_H2I, h2i_b, (float*)d_out);
    } else {
        // fallback: scalar atomic path (~21 MB)
        float* ws    = (float*)d_ws;
        float* fh    = ws;
        float* fx    = fh + NN * HID;
        float* cnt   = fx + NN * 3;
        float* fagg_m = cnt + NN;
        float* fagg_x = fagg_m + NN * HID;

        hipMemsetAsync(cnt, 0, NN * sizeof(float), stream);
        init_fb_kernel<<<256, 256, 0, stream>>>(X_t, edges, fx, cnt);
        node_mlp_kernel<<<NN / 16, 128, 0, stream>>>(H_t, cond, t_in,
                                                     W0, b0, W1, b1, W2, b2, fh);
        for (int l = 0; l < 3; ++l) {
            hipMemsetAsync(fagg_m, 0, (size_t)NN * 131 * sizeof(float), stream);
            edge_gemm_fb_kernel<<<NE / TILE_E, 256, 0, stream>>>(
                fh, fx, edges, etype, edge_table,
                We + (size_t)l * DE * HID, be + l * HID,
                Wx + l * HID, bx + l, fagg_m, fagg_x);
            node_update_fb_kernel<<<NN / 16, 128, 0, stream>>>(
                fh, fx, fagg_m, fagg_x, cnt,
                Wh + (size_t)l * 256 * HID, bh + l * HID);
        }
        final_fb_kernel<<<NN / 8, 64, 0, stream>>>(fh, fx, gmask, h2i_W, h2i_b, (float*)d_out);
    }
}

// Round 14
// 405.644 us; speedup vs baseline: 1.2764x; 1.0212x over previous
//
#include <hip/hip_runtime.h>
#include <math.h>

#define NN 20000
#define NE 256000
#define IN_DIM 64
#define HID 128
#define DE 289     // 2*HID + 1 + 32
#define D0 320     // IN_DIM + 2*HID
#define TILE_E 64
#define NB64 313   // ceil(NN/64)
#define NUB 16     // nodes per block (fused node kernel)
#define SRCMASK 0x3FFFFFFF

typedef unsigned short u16;
typedef unsigned int u32;
typedef unsigned long long u64;
typedef __attribute__((ext_vector_type(8))) short short8;
typedef __attribute__((ext_vector_type(4))) float float4v;

// Bpack layout offsets (u16 elements)
#define OFF_WE   0          // 3 x 40960 (K=289 pad 320, N=128) — tiles 0..3 = We rows 0..255
#define OFF_W0   122880     // 40960 (K=320, N=128)
#define OFF_W1   163840     // 16384 (K=128, N=128)
#define OFF_W2   180224     // 16384
#define OFF_WH   196608     // 3 x 32768 (K=256, N=128)
#define OFF_H2I  294912     // 8192 (K=128, N=64)
#define PACK_TOT 303104

static __device__ __forceinline__ u16 f2bf(float f) {
    unsigned int u = __float_as_uint(f);
    u += 0x7fffu + ((u >> 16) & 1u);
    return (u16)(u >> 16);
}
static __device__ __forceinline__ float bf2f(u16 s) {
    return __uint_as_float(((unsigned int)s) << 16);
}
static __device__ __forceinline__ float bflo(u32 u) { return bf2f((u16)(u & 0xffffu)); }
static __device__ __forceinline__ float bfhi(u32 u) { return bf2f((u16)(u >> 16)); }
static __device__ __forceinline__ uint4 pack8(const float* v) {
    uint4 r;
    r.x = (u32)f2bf(v[0]) | ((u32)f2bf(v[1]) << 16);
    r.y = (u32)f2bf(v[2]) | ((u32)f2bf(v[3]) << 16);
    r.z = (u32)f2bf(v[4]) | ((u32)f2bf(v[5]) << 16);
    r.w = (u32)f2bf(v[6]) | ((u32)f2bf(v[7]) << 16);
    return r;
}
static __device__ __forceinline__ void unpack8(uint4 a, float* o) {
    o[0]=bflo(a.x); o[1]=bfhi(a.x); o[2]=bflo(a.y); o[3]=bfhi(a.y);
    o[4]=bflo(a.z); o[5]=bfhi(a.z); o[6]=bflo(a.w); o[7]=bfhi(a.w);
}
static __device__ __forceinline__ float silu(float v) {
    return v * (1.f / (1.f + __expf(-v)));
}

// ================= CSR build =================
__global__ __launch_bounds__(256) void hist_kernel(
    const float* __restrict__ X_t, const int* __restrict__ edges,
    float* __restrict__ x, int* __restrict__ deg)
{
    int gid = blockIdx.x * blockDim.x + threadIdx.x;
    int stride = gridDim.x * blockDim.x;
    for (int i = gid; i < NN * 3; i += stride) x[i] = X_t[i];
    for (int e = gid; e < NE; e += stride)
        atomicAdd(&deg[edges[NE + e]], 1);
}

__global__ __launch_bounds__(256) void scan_kernel(
    const int* __restrict__ deg, int* __restrict__ row_start, int* __restrict__ head)
{
    __shared__ int s[256];
    int tx = threadIdx.x;
    const int per = (NN + 255) / 256;
    int st = tx * per, en = st + per;
    if (st > NN) st = NN;
    if (en > NN) en = NN;
    int sum = 0;
    for (int i = st; i < en; ++i) sum += deg[i];
    s[tx] = sum;
    __syncthreads();
    for (int off = 1; off < 256; off <<= 1) {
        int t = (tx >= off) ? s[tx - off] : 0;
        __syncthreads();
        s[tx] += t;
        __syncthreads();
    }
    int run = (tx == 0) ? 0 : s[tx - 1];
    for (int i = st; i < en; ++i) {
        row_start[i] = run; head[i] = run; run += deg[i];
    }
    if (tx == 255) row_start[NN] = run;
}

// permute edges into dst-sorted order; pack etype into src bit 30
__global__ __launch_bounds__(256) void scatter_kernel(
    const int* __restrict__ edges, const int* __restrict__ etype,
    int* __restrict__ head,
    int* __restrict__ src_s, int* __restrict__ dst_s)
{
    int gid = blockIdx.x * blockDim.x + threadIdx.x;
    int stride = gridDim.x * blockDim.x;
    for (int e = gid; e < NE; e += stride) {
        int d = edges[NE + e];
        int p = atomicAdd(&head[d], 1);
        src_s[p] = edges[e] | (etype[e] << 30);
        dst_s[p] = d;
    }
}

// ================= weight frag-order packing =================
__global__ __launch_bounds__(256) void pack_all_kernel(
    const float* __restrict__ We, const float* __restrict__ W0,
    const float* __restrict__ W1, const float* __restrict__ W2,
    const float* __restrict__ Wh, const float* __restrict__ h2i,
    u16* __restrict__ Bp)
{
    int idx = blockIdx.x * 256 + threadIdx.x;
    if (idx >= PACK_TOT) return;
    const float* src; int N = 128, Ksrc; int r;
    if (idx < OFF_W0) {
        int layer = idx / 40960; r = idx - layer * 40960;
        src = We + (size_t)layer * DE * HID; Ksrc = DE;
    } else if (idx < OFF_W1) { r = idx - OFF_W0; src = W0; Ksrc = 320; }
    else if (idx < OFF_W2)   { r = idx - OFF_W1; src = W1; Ksrc = 128; }
    else if (idx < OFF_WH)   { r = idx - OFF_W2; src = W2; Ksrc = 128; }
    else if (idx < OFF_H2I) {
        int t = idx - OFF_WH; int layer = t / 32768; r = t - layer * 32768;
        src = Wh + (size_t)layer * 256 * HID; Ksrc = 256;
    } else { r = idx - OFF_H2I; src = h2i; Ksrc = 128; N = 64; }
    int ntc = N / 16;
    int j = r & 7, lane = (r >> 3) & 63;
    int rem = r >> 9;
    int nt = rem % ntc, ks = rem / ntc;
    int k = ks * 32 + ((lane >> 4) << 3) + j;
    int c = nt * 16 + (lane & 15);
    Bp[idx] = f2bf((k < Ksrc) ? src[(size_t)k * N + c] : 0.f);
}

// ================= edge tail precompute (f32) =================
__global__ __launch_bounds__(256) void precomp_tv_kernel(
    const float* __restrict__ edge_table, const float* __restrict__ We,
    const float* __restrict__ be, float* __restrict__ tv, float* __restrict__ wed2)
{
    int idx = blockIdx.x * 256 + threadIdx.x;
    if (idx < 768) {
        int f = idx & 127, t = (idx >> 7) & 1, l = idx >> 8;
        float acc = be[l * 128 + f];
        const float* W = We + (size_t)l * DE * HID;
        #pragma unroll
        for (int k = 0; k < 32; ++k)
            acc += edge_table[t * 32 + k] * W[(size_t)(257 + k) * HID + f];
        tv[l * 256 + t * 128 + f] = acc;
    } else if (idx < 1152) {
        int r = idx - 768;
        int f = r & 127, l = r >> 7;
        wed2[l * 128 + f] = We[(size_t)l * DE * HID + (size_t)256 * HID + f];
    }
}

// ================= per-layer edge geometry: (dx,dy,dz,d2) =================
__global__ __launch_bounds__(256) void geom_kernel(
    const float* __restrict__ x,
    const int* __restrict__ src_s, const int* __restrict__ dst_s,
    float4* __restrict__ geom)
{
    int e = blockIdx.x * 256 + threadIdx.x;
    if (e >= NE) return;
    int s = src_s[e] & SRCMASK, d = dst_s[e];
    float dx = x[s*3+0]-x[d*3+0], dy = x[s*3+1]-x[d*3+1], dz = x[s*3+2]-x[d*3+2];
    geom[e] = make_float4(dx, dy, dz, dx*dx + dy*dy + dz*dz);
}

// ================= node MLP: MFMA, 64 nodes/block =================
__global__ __launch_bounds__(256) void node_mlp_mfma_kernel(
    const float* __restrict__ H_t, const float* __restrict__ cond,
    const float* __restrict__ t_in,
    const u16* __restrict__ W0p, const float* __restrict__ b0,
    const u16* __restrict__ W1p, const float* __restrict__ b1,
    const u16* __restrict__ W2p, const float* __restrict__ b2,
    float* __restrict__ h, u16* __restrict__ h_bf)
{
    __shared__ u16 s_A[64 * 64];
    __shared__ u16 s_B[64 * 128];
    __shared__ u16 s_h[64 * 128];
    __shared__ float s_t[64];

    int tx = threadIdx.x;
    int n0 = blockIdx.x * 64;
    int l = tx & 63, w = tx >> 6;
    int mt_base = (w & 1) * 2, nt_base = (w >> 1) * 4;
    const float cfr = -logf(10000.f) / 63.f;

    if (tx < 64) s_t[tx] = (n0 + tx < NN) ? t_in[n0 + tx] : 0.f;

    float4v acc[2][4];
    #pragma unroll
    for (int mi = 0; mi < 2; ++mi)
        #pragma unroll
        for (int ni = 0; ni < 4; ++ni) acc[mi][ni] = (float4v){0.f,0.f,0.f,0.f};

    for (int t = 0; t < 5; ++t) {
        __syncthreads();
        #pragma unroll
        for (int it = 0; it < 2; ++it) {
            int flat = it * 256 + tx;
            int n = flat >> 3, sl = flat & 7;
            int c = sl ^ (n & 7);
            int k0 = t * 64 + c * 8;
            float tv8[8];
            int gn = n0 + n;
            if (gn < NN) {
                if (k0 < 192) {
                    const float* src = (k0 < 64) ? &H_t[(size_t)gn * IN_DIM + k0]
                                                 : &cond[(size_t)gn * HID + (k0 - 64)];
                    float4 a = *(const float4*)src;
                    float4 b = *(const float4*)(src + 4);
                    tv8[0]=a.x; tv8[1]=a.y; tv8[2]=a.z; tv8[3]=a.w;
                    tv8[4]=b.x; tv8[5]=b.y; tv8[6]=b.z; tv8[7]=b.w;
                } else {
                    float tv = s_t[n];
                    int jj = (k0 - 192) & 63;
                    bool is_sin = (k0 < 256);
                    #pragma unroll
                    for (int jx = 0; jx < 8; ++jx) {
                        float ang = tv * __expf(cfr * (float)(jj + jx));
                        tv8[jx] = is_sin ? __sinf(ang) : __cosf(ang);
                    }
                }
            } else {
                #pragma unroll
                for (int jx = 0; jx < 8; ++jx) tv8[jx] = 0.f;
            }
            *(uint4*)&s_A[n * 64 + sl * 8] = pack8(tv8);
        }
        #pragma unroll
        for (int it = 0; it < 4; ++it) {
            int flat = it * 256 + tx;
            ((uint4*)s_B)[flat] = ((const uint4*)(W0p + (size_t)t * 8192))[flat];
        }
        __syncthreads();
        #pragma unroll
        for (int s = 0; s < 2; ++s) {
            short8 af[2], bfv[4];
            #pragma unroll
            for (int mi = 0; mi < 2; ++mi) {
                int m = (mt_base + mi) * 16 + (l & 15);
                int c = s * 4 + (l >> 4);
                int slot = c ^ (l & 7);
                af[mi] = *(const short8*)(s_A + m * 64 + slot * 8);
            }
            #pragma unroll
            for (int ni = 0; ni < 4; ++ni)
                bfv[ni] = *(const short8*)(s_B + ((s * 8 + nt_base + ni) * 64 + l) * 8);
            #pragma unroll
            for (int mi = 0; mi < 2; ++mi)
                #pragma unroll
                for (int ni = 0; ni < 4; ++ni)
                    acc[mi][ni] = __builtin_amdgcn_mfma_f32_16x16x32_bf16(
                        af[mi], bfv[ni], acc[mi][ni], 0, 0, 0);
        }
    }
    #pragma unroll
    for (int mi = 0; mi < 2; ++mi) {
        #pragma unroll
        for (int ni = 0; ni < 4; ++ni) {
            int f = (nt_base + ni) * 16 + (l & 15);
            float bv = b0[f];
            #pragma unroll
            for (int r = 0; r < 4; ++r) {
                int m = (mt_base + mi) * 16 + (l >> 4) * 4 + r;
                float v = fmaxf(acc[mi][ni][r] + bv, 0.f);
                int slot = (f >> 3) ^ (m & 7);
                s_h[m * 128 + slot * 8 + (f & 7)] = f2bf(v);
            }
            acc[mi][ni] = (float4v){0.f,0.f,0.f,0.f};
        }
    }
    for (int t = 0; t < 2; ++t) {
        __syncthreads();
        #pragma unroll
        for (int it = 0; it < 4; ++it) {
            int flat = it * 256 + tx;
            ((uint4*)s_B)[flat] = ((const uint4*)(W1p + (size_t)t * 8192))[flat];
        }
        __syncthreads();
        #pragma unroll
        for (int s = 0; s < 2; ++s) {
            short8 af[2], bfv[4];
            #pragma unroll
            for (int mi = 0; mi < 2; ++mi) {
                int m = (mt_base + mi) * 16 + (l & 15);
                int c = t * 8 + s * 4 + (l >> 4);
                int slot = c ^ (l & 7);
                af[mi] = *(const short8*)(s_h + m * 128 + slot * 8);
            }
            #pragma unroll
            for (int ni = 0; ni < 4; ++ni)
                bfv[ni] = *(const short8*)(s_B + ((s * 8 + nt_base + ni) * 64 + l) * 8);
            #pragma unroll
            for (int mi = 0; mi < 2; ++mi)
                #pragma unroll
                for (int ni = 0; ni < 4; ++ni)
                    acc[mi][ni] = __builtin_amdgcn_mfma_f32_16x16x32_bf16(
                        af[mi], bfv[ni], acc[mi][ni], 0, 0, 0);
        }
    }
    __syncthreads();
    #pragma unroll
    for (int mi = 0; mi < 2; ++mi) {
        #pragma unroll
        for (int ni = 0; ni < 4; ++ni) {
            int f = (nt_base + ni) * 16 + (l & 15);
            float bv = b1[f];
            #pragma unroll
            for (int r = 0; r < 4; ++r) {
                int m = (mt_base + mi) * 16 + (l >> 4) * 4 + r;
                float v = fmaxf(acc[mi][ni][r] + bv, 0.f);
                int slot = (f >> 3) ^ (m & 7);
                s_h[m * 128 + slot * 8 + (f & 7)] = f2bf(v);
            }
            acc[mi][ni] = (float4v){0.f,0.f,0.f,0.f};
        }
    }
    for (int t = 0; t < 2; ++t) {
        __syncthreads();
        #pragma unroll
        for (int it = 0; it < 4; ++it) {
            int flat = it * 256 + tx;
            ((uint4*)s_B)[flat] = ((const uint4*)(W2p + (size_t)t * 8192))[flat];
        }
        __syncthreads();
        #pragma unroll
        for (int s = 0; s < 2; ++s) {
            short8 af[2], bfv[4];
            #pragma unroll
            for (int mi = 0; mi < 2; ++mi) {
                int m = (mt_base + mi) * 16 + (l & 15);
                int c = t * 8 + s * 4 + (l >> 4);
                int slot = c ^ (l & 7);
                af[mi] = *(const short8*)(s_h + m * 128 + slot * 8);
            }
            #pragma unroll
            for (int ni = 0; ni < 4; ++ni)
                bfv[ni] = *(const short8*)(s_B + ((s * 8 + nt_base + ni) * 64 + l) * 8);
            #pragma unroll
            for (int mi = 0; mi < 2; ++mi)
                #pragma unroll
                for (int ni = 0; ni < 4; ++ni)
                    acc[mi][ni] = __builtin_amdgcn_mfma_f32_16x16x32_bf16(
                        af[mi], bfv[ni], acc[mi][ni], 0, 0, 0);
        }
    }
    #pragma unroll
    for (int mi = 0; mi < 2; ++mi) {
        #pragma unroll
        for (int ni = 0; ni < 4; ++ni) {
            int f = (nt_base + ni) * 16 + (l & 15);
            float bv = b2[f];
            #pragma unroll
            for (int r = 0; r < 4; ++r) {
                int m = (mt_base + mi) * 16 + (l >> 4) * 4 + r;
                int gn = n0 + m;
                if (gn < NN) {
                    float v = acc[mi][ni][r] + bv;
                    h[(size_t)gn * HID + f] = v;
                    h_bf[(size_t)gn * HID + f] = f2bf(v);
                }
            }
        }
    }
}

// ================= cvec: C[n][0:128]=h@We_src, C[n][128:256]=h@We_dst (bf16 out) =================
__global__ __launch_bounds__(256) void cvec_kernel(
    const u16* __restrict__ h_bf, const u16* __restrict__ WEp,
    u16* __restrict__ Cbf)
{
    __shared__ u16 s_A[64 * 64];
    __shared__ u16 s_B[64 * 128];

    int tx = threadIdx.x;
    int n0 = blockIdx.x * 64;
    int l = tx & 63, w = tx >> 6;
    int mt_base = (w & 1) * 2, nt_base = (w >> 1) * 4;

    float4v acc[2][2][4];  // [side][mi][ni]
    #pragma unroll
    for (int sd = 0; sd < 2; ++sd)
        #pragma unroll
        for (int mi = 0; mi < 2; ++mi)
            #pragma unroll
            for (int ni = 0; ni < 4; ++ni)
                acc[sd][mi][ni] = (float4v){0.f,0.f,0.f,0.f};

    for (int t = 0; t < 4; ++t) {
        __syncthreads();
        #pragma unroll
        for (int it = 0; it < 2; ++it) {
            int flat = it * 256 + tx;
            int n = flat >> 3, sl = flat & 7;
            int c = sl ^ (n & 7);
            int gn = n0 + n;
            uint4 v = make_uint4(0,0,0,0);
            if (gn < NN) v = *(const uint4*)(h_bf + (size_t)gn * 128 + (t & 1) * 64 + c * 8);
            *(uint4*)&s_A[n * 64 + sl * 8] = v;
        }
        #pragma unroll
        for (int it = 0; it < 4; ++it) {
            int flat = it * 256 + tx;
            ((uint4*)s_B)[flat] = ((const uint4*)(WEp + (size_t)t * 8192))[flat];
        }
        __syncthreads();
        int sd = t >> 1;
        #pragma unroll
        for (int s = 0; s < 2; ++s) {
            short8 af[2], bfv[4];
            #pragma unroll
            for (int mi = 0; mi < 2; ++mi) {
                int m = (mt_base + mi) * 16 + (l & 15);
                int c = s * 4 + (l >> 4);
                int slot = c ^ (l & 7);
                af[mi] = *(const short8*)(s_A + m * 64 + slot * 8);
            }
            #pragma unroll
            for (int ni = 0; ni < 4; ++ni)
                bfv[ni] = *(const short8*)(s_B + ((s * 8 + nt_base + ni) * 64 + l) * 8);
            #pragma unroll
            for (int mi = 0; mi < 2; ++mi)
                #pragma unroll
                for (int ni = 0; ni < 4; ++ni)
                    acc[sd][mi][ni] = __builtin_amdgcn_mfma_f32_16x16x32_bf16(
                        af[mi], bfv[ni], acc[sd][mi][ni], 0, 0, 0);
        }
    }
    #pragma unroll
    for (int sd = 0; sd < 2; ++sd) {
        #pragma unroll
        for (int mi = 0; mi < 2; ++mi) {
            #pragma unroll
            for (int ni = 0; ni < 4; ++ni) {
                int f = sd * 128 + (nt_base + ni) * 16 + (l & 15);
                #pragma unroll
                for (int r = 0; r < 4; ++r) {
                    int m = (mt_base + mi) * 16 + (l >> 4) * 4 + r;
                    int gn = n0 + m;
                    if (gn < NN)
                        Cbf[(size_t)gn * 256 + f] = f2bf(acc[sd][mi][ni][r]);
                }
            }
        }
    }
}

// ================= fused node update v3: 512 thr, 2-way parity, deferred reductions =================
// thread: node i = tx>>5, edge-parity q = (tx>>4)&1, feat-chunk p = tx&15 (8 feats)
__global__ __launch_bounds__(512) void node_fused_kernel(
    float* __restrict__ h, u16* __restrict__ h_bf, float* __restrict__ x,
    const u16* __restrict__ Cbf, const float4* __restrict__ geom,
    const int* __restrict__ src_s,
    const int* __restrict__ row_start,
    const float* __restrict__ tv_l, const float* __restrict__ wed2_l,
    const float* __restrict__ Wx_l, const float* __restrict__ bx_l,
    const u16* __restrict__ Whp_l, const float* __restrict__ bh_l)
{
    __shared__ u16 s_A[NUB * 256];   // 8 KB: [node][256k] xor-swizzled: h | agg
    __shared__ u16 s_B[64 * 128];    // 16 KB
    __shared__ int s_rs[NUB + 1];

    int tx = threadIdx.x;
    int n0 = blockIdx.x * NUB;
    int l = tx & 63, w = tx >> 6;    // 8 waves

    if (tx < NUB + 1) s_rs[tx] = row_start[n0 + tx];
    // stage h_bf (chunks 0..15)
    if (tx < 256) {
        int n = tx >> 4, c = tx & 15;
        int slot = c ^ (n & 7);
        uint4 v = *(const uint4*)(h_bf + (size_t)(n0 + n) * 128 + c * 8);
        *(uint4*)&s_A[n * 256 + slot * 8] = v;
    }
    __syncthreads();
    // fused message + aggregation (2 parities per node)
    {
        int i = tx >> 5, q = (tx >> 4) & 1, p = tx & 15;
        int gn = n0 + i;
        int rs = s_rs[i], re = s_rs[i + 1];
        float cdv[8], c0[8], c1[8], wed[8], wx[8];
        unpack8(*(const uint4*)(Cbf + (size_t)gn * 256 + 128 + p * 8), cdv);
        #pragma unroll
        for (int qq = 0; qq < 2; ++qq) {
            float4 a0 = *(const float4*)(tv_l + p * 8 + qq * 4);
            float4 a1 = *(const float4*)(tv_l + 128 + p * 8 + qq * 4);
            float4 a2 = *(const float4*)(wed2_l + p * 8 + qq * 4);
            float4 a3 = *(const float4*)(Wx_l + p * 8 + qq * 4);
            c0[qq*4+0]=a0.x; c0[qq*4+1]=a0.y; c0[qq*4+2]=a0.z; c0[qq*4+3]=a0.w;
            c1[qq*4+0]=a1.x; c1[qq*4+1]=a1.y; c1[qq*4+2]=a1.z; c1[qq*4+3]=a1.w;
            wed[qq*4+0]=a2.x; wed[qq*4+1]=a2.y; wed[qq*4+2]=a2.z; wed[qq*4+3]=a2.w;
            wx[qq*4+0]=a3.x; wx[qq*4+1]=a3.y; wx[qq*4+2]=a3.z; wx[qq*4+3]=a3.w;
        }
        #pragma unroll
        for (int f = 0; f < 8; ++f) { c0[f] += cdv[f]; c1[f] += cdv[f]; }
        float bx16 = bx_l[0] * 0.0625f;
        float ag[8];
        #pragma unroll
        for (int f = 0; f < 8; ++f) ag[f] = 0.f;
        float sx = 0.f, sy = 0.f, sz = 0.f;

        int j = rs + q;
        if (j < re) {
            int sp = src_s[j];
            float4 g = geom[j];
            uint4 craw = *(const uint4*)(Cbf + (size_t)(sp & SRCMASK) * 256 + p * 8);
            int et = sp >> 30;
            while (1) {
                int jn = j + 2;
                bool more = (jn < re);
                int sp2 = 0; float4 g2 = g; uint4 craw2 = craw;
                if (more) {
                    sp2 = src_s[jn];
                    g2 = geom[jn];
                    craw2 = *(const uint4*)(Cbf + (size_t)(sp2 & SRCMASK) * 256 + p * 8);
                }
                float av[8];
                unpack8(craw, av);
                float wpart = 0.f;
                #pragma unroll
                for (int f = 0; f < 8; ++f) {
                    float v = av[f] + (et ? c1[f] : c0[f]) + g.w * wed[f];
                    float m = silu(v);
                    ag[f] += m;
                    wpart += m * wx[f];
                }
                wpart += bx16;
                sx += g.x * wpart;
                sy += g.y * wpart;
                sz += g.z * wpart;
                if (!more) break;
                j = jn; g = g2; craw = craw2; et = sp2 >> 30;
            }
        }
        // combine parities for ag (lane XOR 16 stays within this node's 32-lane group)
        #pragma unroll
        for (int f = 0; f < 8; ++f) ag[f] += __shfl_xor(ag[f], 16);
        // reduce sx,sy,sz over all 32 lanes of this node (feat lanes + parity)
        #pragma unroll
        for (int off = 1; off <= 16; off <<= 1) {
            sx += __shfl_xor(sx, off);
            sy += __shfl_xor(sy, off);
            sz += __shfl_xor(sz, off);
        }
        if (q == 0) {
            int c2 = 16 + p;
            int slot = c2 ^ (i & 7);
            *(uint4*)&s_A[i * 256 + slot * 8] = pack8(ag);
            if (p == 0) {
                float inv = 1.f / ((float)(re - rs) + 1.f);
                x[gn * 3 + 0] += sx * inv;
                x[gn * 3 + 1] += sy * inv;
                x[gn * 3 + 2] += sz * inv;
            }
        }
    }

    // Wh GEMM: 8 waves, wave w covers N-tile w (16 feats)
    float4v acc = (float4v){0.f, 0.f, 0.f, 0.f};
    for (int t = 0; t < 4; ++t) {
        __syncthreads();
        #pragma unroll
        for (int it = 0; it < 2; ++it) {
            int flat = it * 512 + tx;
            ((uint4*)s_B)[flat] = ((const uint4*)(Whp_l + (size_t)t * 8192))[flat];
        }
        __syncthreads();
        #pragma unroll
        for (int s = 0; s < 2; ++s) {
            short8 af, bfv;
            {
                int m = l & 15;
                int c = t * 8 + s * 4 + (l >> 4);
                int slot = c ^ (l & 7);
                af = *(const short8*)(s_A + m * 256 + slot * 8);
            }
            bfv = *(const short8*)(s_B + ((s * 8 + w) * 64 + l) * 8);
            acc = __builtin_amdgcn_mfma_f32_16x16x32_bf16(af, bfv, acc, 0, 0, 0);
        }
    }
    // epilogue: h += silu(acc + bh)
    {
        int f = w * 16 + (l & 15);
        float bv = bh_l[f];
        #pragma unroll
        for (int r = 0; r < 4; ++r) {
            int m = (l >> 4) * 4 + r;
            int gn = n0 + m;
            float v = acc[r] + bv;
            float hn = h[(size_t)gn * HID + f] + silu(v);
            h[(size_t)gn * HID + f] = hn;
            h_bf[(size_t)gn * HID + f] = f2bf(hn);
        }
    }
}

// ================= final: MFMA h2i, 64 nodes/block =================
__global__ __launch_bounds__(256) void final_mfma_kernel(
    const u16* __restrict__ h_bf, const float* __restrict__ x,
    const int* __restrict__ gmask,
    const u16* __restrict__ h2ip, const float* __restrict__ b,
    float* __restrict__ out)
{
    __shared__ u16 s_A[64 * 128];
    __shared__ u16 s_B[4096];

    int tx = threadIdx.x;
    int n0 = blockIdx.x * 64;
    int l = tx & 63, w = tx >> 6;
    int mt_base = (w & 1) * 2, nt_base = (w >> 1) * 2;

    #pragma unroll
    for (int it = 0; it < 4; ++it) {
        int flat = it * 256 + tx;
        int n = flat >> 4, c = flat & 15;
        int slot = c ^ (n & 7);
        int gn = n0 + n;
        uint4 v = make_uint4(0,0,0,0);
        if (gn < NN) v = *(const uint4*)(h_bf + (size_t)gn * 128 + c * 8);
        *(uint4*)&s_A[n * 128 + slot * 8] = v;
    }

    float4v acc[2][2];
    #pragma unroll
    for (int mi = 0; mi < 2; ++mi)
        #pragma unroll
        for (int ni = 0; ni < 2; ++ni) acc[mi][ni] = (float4v){0.f,0.f,0.f,0.f};

    for (int t = 0; t < 2; ++t) {
        __syncthreads();
        #pragma unroll
        for (int it = 0; it < 2; ++it) {
            int flat = it * 256 + tx;
            ((uint4*)s_B)[flat] = ((const uint4*)(h2ip + (size_t)t * 4096))[flat];
        }
        __syncthreads();
        #pragma unroll
        for (int s = 0; s < 2; ++s) {
            short8 af[2], bfv[2];
            #pragma unroll
            for (int mi = 0; mi < 2; ++mi) {
                int m = (mt_base + mi) * 16 + (l & 15);
                int c = t * 8 + s * 4 + (l >> 4);
                int slot = c ^ (l & 7);
                af[mi] = *(const short8*)(s_A + m * 128 + slot * 8);
            }
            #pragma unroll
            for (int ni = 0; ni < 2; ++ni)
                bfv[ni] = *(const short8*)(s_B + ((s * 4 + nt_base + ni) * 64 + l) * 8);
            #pragma unroll
            for (int mi = 0; mi < 2; ++mi)
                #pragma unroll
                for (int ni = 0; ni < 2; ++ni)
                    acc[mi][ni] = __builtin_amdgcn_mfma_f32_16x16x32_bf16(
                        af[mi], bfv[ni], acc[mi][ni], 0, 0, 0);
        }
    }
    #pragma unroll
    for (int mi = 0; mi < 2; ++mi) {
        #pragma unroll
        for (int ni = 0; ni < 2; ++ni) {
            int f = (nt_base + ni) * 16 + (l & 15);
            float bv = b[f];
            #pragma unroll
            for (int r = 0; r < 4; ++r) {
                int m = (mt_base + mi) * 16 + (l >> 4) * 4 + r;
                int gn = n0 + m;
                if (gn < NN)
                    out[(size_t)gn * IN_DIM + f] = gmask[gn] ? (acc[mi][ni][r] + bv) : 0.f;
            }
        }
    }
    if (tx < 192) {
        int i = tx / 3, c = tx % 3;
        int gn = n0 + i;
        if (gn < NN)
            out[(size_t)NN * IN_DIM + gn * 3 + c] = gmask[gn] ? x[gn * 3 + c] : 0.f;
    }
}

// ================= fallback path (atomic, scalar; used only if ws too small) =================
__global__ __launch_bounds__(256) void init_fb_kernel(
    const float* __restrict__ X_t, const int* __restrict__ edges,
    float* __restrict__ x, float* __restrict__ cnt)
{
    int gid = blockIdx.x * blockDim.x + threadIdx.x;
    int stride = gridDim.x * blockDim.x;
    for (int i = gid; i < NN * 3; i += stride) x[i] = X_t[i];
    for (int e = gid; e < NE; e += stride)
        atomicAdd(&cnt[edges[NE + e]], 1.0f);
}

__global__ __launch_bounds__(128) void node_mlp_kernel(
    const float* __restrict__ H_t, const float* __restrict__ cond,
    const float* __restrict__ t_in,
    const float* __restrict__ W0, const float* __restrict__ b0,
    const float* __restrict__ W1, const float* __restrict__ b1,
    const float* __restrict__ W2, const float* __restrict__ b2,
    float* __restrict__ h)
{
    __shared__ float s_feat[D0][20];
    __shared__ float s_h0[HID][20];
    __shared__ float s_h1[HID][20];
    int n0 = blockIdx.x * 16;
    int tx = threadIdx.x;

    for (int idx = tx; idx < 16 * IN_DIM; idx += 128) {
        int i = idx >> 6, k = idx & 63;
        s_feat[k][i] = H_t[(n0 + i) * IN_DIM + k];
    }
    for (int idx = tx; idx < 16 * HID; idx += 128) {
        int i = idx >> 7, k = idx & 127;
        s_feat[IN_DIM + k][i] = cond[(n0 + i) * HID + k];
    }
    const float cfr = -logf(10000.f) / 63.f;
    for (int idx = tx; idx < 16 * HID; idx += 128) {
        int i = idx >> 7, k = idx & 127;
        float tv = t_in[n0 + i];
        int jj = k & 63;
        float ang = tv * __expf(cfr * (float)jj);
        s_feat[IN_DIM + HID + k][i] = (k < 64) ? __sinf(ang) : __cosf(ang);
    }
    __syncthreads();

    float acc[16];
    {
        float bv = b0[tx];
        #pragma unroll
        for (int i = 0; i < 16; ++i) acc[i] = bv;
        for (int k = 0; k < D0; ++k) {
            float w = W0[k * HID + tx];
            float4 f0 = *(const float4*)&s_feat[k][0];
            float4 f1 = *(const float4*)&s_feat[k][4];
            float4 f2 = *(const float4*)&s_feat[k][8];
            float4 f3 = *(const float4*)&s_feat[k][12];
            acc[0] += f0.x*w; acc[1] += f0.y*w; acc[2] += f0.z*w; acc[3] += f0.w*w;
            acc[4] += f1.x*w; acc[5] += f1.y*w; acc[6] += f1.z*w; acc[7] += f1.w*w;
            acc[8] += f2.x*w; acc[9] += f2.y*w; acc[10]+= f2.z*w; acc[11]+= f2.w*w;
            acc[12]+= f3.x*w; acc[13]+= f3.y*w; acc[14]+= f3.z*w; acc[15]+= f3.w*w;
        }
        #pragma unroll
        for (int i = 0; i < 16; ++i) s_h0[tx][i] = fmaxf(acc[i], 0.f);
    }
    __syncthreads();
    {
        float bv = b1[tx];
        #pragma unroll
        for (int i = 0; i < 16; ++i) acc[i] = bv;
        for (int k = 0; k < HID; ++k) {
            float w = W1[k * HID + tx];
            float4 f0 = *(const float4*)&s_h0[k][0];
            float4 f1 = *(const float4*)&s_h0[k][4];
            float4 f2 = *(const float4*)&s_h0[k][8];
            float4 f3 = *(const float4*)&s_h0[k][12];
            acc[0] += f0.x*w; acc[1] += f0.y*w; acc[2] += f0.z*w; acc[3] += f0.w*w;
            acc[4] += f1.x*w; acc[5] += f1.y*w; acc[6] += f1.z*w; acc[7] += f1.w*w;
            acc[8] += f2.x*w; acc[9] += f2.y*w; acc[10]+= f2.z*w; acc[11]+= f2.w*w;
            acc[12]+= f3.x*w; acc[13]+= f3.y*w; acc[14]+= f3.z*w; acc[15]+= f3.w*w;
        }
        #pragma unroll
        for (int i = 0; i < 16; ++i) s_h1[tx][i] = fmaxf(acc[i], 0.f);
    }
    __syncthreads();
    {
        float bv = b2[tx];
        #pragma unroll
        for (int i = 0; i < 16; ++i) acc[i] = bv;
        for (int k = 0; k < HID; ++k) {
            float w = W2[k * HID + tx];
            float4 f0 = *(const float4*)&s_h1[k][0];
            float4 f1 = *(const float4*)&s_h1[k][4];
            float4 f2 = *(const float4*)&s_h1[k][8];
            float4 f3 = *(const float4*)&s_h1[k][12];
            acc[0] += f0.x*w; acc[1] += f0.y*w; acc[2] += f0.z*w; acc[3] += f0.w*w;
            acc[4] += f1.x*w; acc[5] += f1.y*w; acc[6] += f1.z*w; acc[7] += f1.w*w;
            acc[8] += f2.x*w; acc[9] += f2.y*w; acc[10]+= f2.z*w; acc[11]+= f2.w*w;
            acc[12]+= f3.x*w; acc[13]+= f3.y*w; acc[14]+= f3.z*w; acc[15]+= f3.w*w;
        }
        #pragma unroll
        for (int i = 0; i < 16; ++i) h[(n0 + i) * HID + tx] = acc[i];
    }
}

__global__ __launch_bounds__(256) void edge_gemm_fb_kernel(
    const float* __restrict__ h, const float* __restrict__ x,
    const int* __restrict__ edges, const int* __restrict__ etype,
    const float* __restrict__ edge_table,
    const float* __restrict__ We_l, const float* __restrict__ be_l,
    const float* __restrict__ Wx_l, const float* __restrict__ bx_l,
    float* __restrict__ agg_m, float* __restrict__ agg_x)
{
    __shared__ int s_src[TILE_E], s_dst[TILE_E];
    __shared__ float s_diff[TILE_E][3];
    __shared__ float s_tail[TILE_E][36];
    __shared__ float s_Af[TILE_E][36];
    __shared__ float s_Bf[33][HID];
    __shared__ float s_wx[HID];

    int e0 = blockIdx.x * TILE_E;
    int tx = threadIdx.x;
    int tf = tx & 15;
    int te = tx >> 4;

    if (tx < TILE_E) {
        int s = edges[e0 + tx];
        int d = edges[NE + e0 + tx];
        s_src[tx] = s; s_dst[tx] = d;
        float dx = x[s * 3 + 0] - x[d * 3 + 0];
        float dy = x[s * 3 + 1] - x[d * 3 + 1];
        float dz = x[s * 3 + 2] - x[d * 3 + 2];
        s_diff[tx][0] = dx; s_diff[tx][1] = dy; s_diff[tx][2] = dz;
        s_tail[tx][0] = dx * dx + dy * dy + dz * dz;
        int et = etype[e0 + tx];
        #pragma unroll
        for (int j = 0; j < 32; ++j) s_tail[tx][1 + j] = edge_table[et * 32 + j];
    }
    if (tx < HID) s_wx[tx] = Wx_l[tx];
    __syncthreads();

    float acc[4][8];
    #pragma unroll
    for (int i = 0; i < 4; ++i)
        #pragma unroll
        for (int j = 0; j < 8; ++j) acc[i][j] = 0.f;

    for (int t = 0; t < 9; ++t) {
        int k0 = t * 32;
        int klen = (t == 8) ? 33 : 32;
        __syncthreads();
        if (t < 8) {
            const bool use_src = (t < 4);
            int kbase = (t & 3) * 32;
            for (int q4 = tx; q4 < TILE_E * 8; q4 += 256) {
                int e = q4 >> 3, q = q4 & 7;
                int row = use_src ? s_src[e] : s_dst[e];
                float4 v = *(const float4*)&h[row * HID + kbase + q * 4];
                *(float4*)&s_Af[e][q * 4] = v;
            }
        }
        for (int q4 = tx; q4 < klen * 32; q4 += 256) {
            int kk = q4 >> 5, c4 = q4 & 31;
            float4 v = *(const float4*)&We_l[(k0 + kk) * HID + c4 * 4];
            *(float4*)&s_Bf[kk][c4 * 4] = v;
        }
        __syncthreads();
        const float (*Asrc)[36] = (t == 8) ? (const float (*)[36])s_tail
                                           : (const float (*)[36])s_Af;
        for (int kk = 0; kk < klen; ++kk) {
            float a0 = Asrc[te * 4 + 0][kk];
            float a1 = Asrc[te * 4 + 1][kk];
            float a2 = Asrc[te * 4 + 2][kk];
            float a3 = Asrc[te * 4 + 3][kk];
            float4 bv0 = *(const float4*)&s_Bf[kk][tf * 8];
            float4 bv1 = *(const float4*)&s_Bf[kk][tf * 8 + 4];
            float b[8] = {bv0.x, bv0.y, bv0.z, bv0.w, bv1.x, bv1.y, bv1.z, bv1.w};
            #pragma unroll
            for (int j = 0; j < 8; ++j) {
                acc[0][j] += a0 * b[j];
                acc[1][j] += a1 * b[j];
                acc[2][j] += a2 * b[j];
                acc[3][j] += a3 * b[j];
            }
        }
    }

    float wsum[4];
    #pragma unroll
    for (int i = 0; i < 4; ++i) {
        float p = 0.f;
        #pragma unroll
        for (int j = 0; j < 8; ++j) {
            int f = tf * 8 + j;
            float v = acc[i][j] + be_l[f];
            float m = silu(v);
            acc[i][j] = m;
            p += m * s_wx[f];
        }
        wsum[i] = p;
    }
    #pragma unroll
    for (int off = 1; off < 16; off <<= 1) {
        #pragma unroll
        for (int i = 0; i < 4; ++i) wsum[i] += __shfl_xor(wsum[i], off);
    }
    float bxv = bx_l[0];
    if (tf < 3) {
        #pragma unroll
        for (int i = 0; i < 4; ++i) {
            int e = te * 4 + i;
            float w2 = wsum[i] + bxv;
            atomicAdd(&agg_x[s_dst[e] * 3 + tf], s_diff[e][tf] * w2);
        }
    }
    #pragma unroll
    for (int i = 0; i < 4; ++i) {
        int d = s_dst[te * 4 + i];
        #pragma unroll
        for (int j = 0; j < 8; ++j)
            atomicAdd(&agg_m[d * HID + tf * 8 + j], acc[i][j]);
    }
}

__global__ __launch_bounds__(128) void node_update_fb_kernel(
    float* __restrict__ h, float* __restrict__ x,
    const float* __restrict__ agg_m, const float* __restrict__ agg_x,
    const float* __restrict__ cnt,
    const float* __restrict__ Wh_l, const float* __restrict__ bh_l)
{
    __shared__ float s_in[256][20];
    int n0 = blockIdx.x * 16;
    int tx = threadIdx.x;
    for (int idx = tx; idx < 16 * HID; idx += 128) {
        int i = idx >> 7, k = idx & 127;
        s_in[k][i] = h[(n0 + i) * HID + k];
    }
    for (int idx = tx; idx < 16 * HID; idx += 128) {
        int i = idx >> 7, k = idx & 127;
        s_in[HID + k][i] = agg_m[(n0 + i) * HID + k];
    }
    __syncthreads();
    float acc[16];
    float bv = bh_l[tx];
    #pragma unroll
    for (int i = 0; i < 16; ++i) acc[i] = bv;
    for (int k = 0; k < 256; ++k) {
        float w = Wh_l[k * HID + tx];
        float4 f0 = *(const float4*)&s_in[k][0];
        float4 f1 = *(const float4*)&s_in[k][4];
        float4 f2 = *(const float4*)&s_in[k][8];
        float4 f3 = *(const float4*)&s_in[k][12];
        acc[0] += f0.x*w; acc[1] += f0.y*w; acc[2] += f0.z*w; acc[3] += f0.w*w;
        acc[4] += f1.x*w; acc[5] += f1.y*w; acc[6] += f1.z*w; acc[7] += f1.w*w;
        acc[8] += f2.x*w; acc[9] += f2.y*w; acc[10]+= f2.z*w; acc[11]+= f2.w*w;
        acc[12]+= f3.x*w; acc[13]+= f3.y*w; acc[14]+= f3.z*w; acc[15]+= f3.w*w;
    }
    #pragma unroll
    for (int i = 0; i < 16; ++i) {
        float v = acc[i];
        h[(n0 + i) * HID + tx] = s_in[tx][i] + silu(v);
    }
    if (tx < 48) {
        int i = tx / 3, c = tx % 3;
        int n = n0 + i;
        x[n * 3 + c] += agg_x[n * 3 + c] / (cnt[n] + 1.f);
    }
}

__global__ __launch_bounds__(64) void final_fb_kernel(
    const float* __restrict__ h, const float* __restrict__ x,
    const int* __restrict__ gmask,
    const float* __restrict__ W, const float* __restrict__ b,
    float* __restrict__ out)
{
    __shared__ float s_h[8][HID];
    int n0 = blockIdx.x * 8;
    int tx = threadIdx.x;
    for (int idx = tx; idx < 8 * HID; idx += 64) {
        int i = idx >> 7, k = idx & 127;
        s_h[i][k] = h[(n0 + i) * HID + k];
    }
    __syncthreads();
    float acc[8];
    float bv = b[tx];
    #pragma unroll
    for (int i = 0; i < 8; ++i) acc[i] = bv;
    for (int k = 0; k < HID; ++k) {
        float w = W[k * IN_DIM + tx];
        #pragma unroll
        for (int i = 0; i < 8; ++i) acc[i] += s_h[i][k] * w;
    }
    #pragma unroll
    for (int i = 0; i < 8; ++i) {
        int n = n0 + i;
        out[n * IN_DIM + tx] = gmask[n] ? acc[i] : 0.f;
    }
    if (tx < 24) {
        int i = tx / 3, c = tx % 3;
        int n = n0 + i;
        out[NN * IN_DIM + n * 3 + c] = gmask[n] ? x[n * 3 + c] : 0.f;
    }
}

extern "C" void kernel_launch(void* const* d_in, const int* in_sizes, int n_in,
                              void* d_out, int out_size, void* d_ws, size_t ws_size,
                              hipStream_t stream) {
    const float* H_t   = (const float*)d_in[0];
    const float* X_t   = (const float*)d_in[1];
    const float* cond  = (const float*)d_in[2];
    const float* t_in  = (const float*)d_in[3];
    const int*   edges = (const int*)d_in[4];
    const int*   etype = (const int*)d_in[5];
    const int*   gmask = (const int*)d_in[6];
    const float* W0 = (const float*)d_in[8];
    const float* b0 = (const float*)d_in[9];
    const float* W1 = (const float*)d_in[10];
    const float* b1 = (const float*)d_in[11];
    const float* W2 = (const float*)d_in[12];
    const float* b2 = (const float*)d_in[13];
    const float* edge_table = (const float*)d_in[14];
    const float* We = (const float*)d_in[15];
    const float* be = (const float*)d_in[16];
    const float* Wx = (const float*)d_in[17];
    const float* bx = (const float*)d_in[18];
    const float* Wh = (const float*)d_in[19];
    const float* bh = (const float*)d_in[20];
    const float* h2i_W = (const float*)d_in[21];
    const float* h2i_b = (const float*)d_in[22];

    char* p = (char*)d_ws;
    float* h = (float*)p;           p += (size_t)NN * HID * 4;
    u16* h_bf = (u16*)p;            p += (size_t)NN * HID * 2;
    float* x = (float*)p;           p += (size_t)NN * 3 * 4;
    u16* Cbf = (u16*)p;             p += (size_t)NN * 256 * 2;
    float4* geom = (float4*)p;      p += (size_t)NE * 16;
    u16* Bpack = (u16*)p;           p += (size_t)PACK_TOT * 2;
    float* tv = (float*)p;          p += (size_t)768 * 4;
    float* wed2 = (float*)p;        p += (size_t)384 * 4;
    int* row_start = (int*)p;       p += (size_t)(NN + 4) * 4;
    int* deg = (int*)p;             p += (size_t)NN * 4;
    int* head = (int*)p;            p += (size_t)NN * 4;
    int* src_s = (int*)p;           p += (size_t)NE * 4;
    int* dst_s = (int*)p;           p += (size_t)NE * 4;
    size_t need = (size_t)(p - (char*)d_ws);

    if (ws_size >= need) {
        hipMemsetAsync(deg, 0, NN * sizeof(int), stream);
        hist_kernel<<<256, 256, 0, stream>>>(X_t, edges, x, deg);
        scan_kernel<<<1, 256, 0, stream>>>(deg, row_start, head);
        scatter_kernel<<<256, 256, 0, stream>>>(edges, etype, head, src_s, dst_s);
        pack_all_kernel<<<(PACK_TOT + 255) / 256, 256, 0, stream>>>(
            We, W0, W1, W2, Wh, h2i_W, Bpack);
        precomp_tv_kernel<<<5, 256, 0, stream>>>(edge_table, We, be, tv, wed2);
        node_mlp_mfma_kernel<<<NB64, 256, 0, stream>>>(
            H_t, cond, t_in,
            Bpack + OFF_W0, b0, Bpack + OFF_W1, b1, Bpack + OFF_W2, b2,
            h, h_bf);
        for (int l = 0; l < 3; ++l) {
            cvec_kernel<<<NB64, 256, 0, stream>>>(
                h_bf, Bpack + OFF_WE + (size_t)l * 40960, Cbf);
            geom_kernel<<<(NE + 255) / 256, 256, 0, stream>>>(x, src_s, dst_s, geom);
            node_fused_kernel<<<NN / NUB, 512, 0, stream>>>(
                h, h_bf, x, Cbf, geom, src_s, row_start,
                tv + (size_t)l * 256, wed2 + (size_t)l * 128,
                Wx + l * HID, bx + l,
                Bpack + OFF_WH + (size_t)l * 32768, bh + l * HID);
        }
        final_mfma_kernel<<<NB64, 256, 0, stream>>>(
            h_bf, x, gmask, Bpack + OFF_H2I, h2i_b, (float*)d_out);
    } else {
        // fallback: scalar atomic path (~21 MB)
        float* ws    = (float*)d_ws;
        float* fh    = ws;
        float* fx    = fh + NN * HID;
        float* cnt   = fx + NN * 3;
        float* fagg_m = cnt + NN;
        float* fagg_x = fagg_m + NN * HID;

        hipMemsetAsync(cnt, 0, NN * sizeof(float), stream);
        init_fb_kernel<<<256, 256, 0, stream>>>(X_t, edges, fx, cnt);
        node_mlp_kernel<<<NN / 16, 128, 0, stream>>>(H_t, cond, t_in,
                                                     W0, b0, W1, b1, W2, b2, fh);
        for (int l = 0; l < 3; ++l) {
            hipMemsetAsync(fagg_m, 0, (size_t)NN * 131 * sizeof(float), stream);
            edge_gemm_fb_kernel<<<NE / TILE_E, 256, 0, stream>>>(
                fh, fx, edges, etype, edge_table,
                We + (size_t)l * DE * HID, be + l * HID,
                Wx + l * HID, bx + l, fagg_m, fagg_x);
            node_update_fb_kernel<<<NN / 16, 128, 0, stream>>>(
                fh, fx, fagg_m, fagg_x, cnt,
                Wh + (size_t)l * 256 * HID, bh + l * HID);
        }
        final_fb_kernel<<<NN / 8, 64, 0, stream>>>(fh, fx, gmask, h2i_W, h2i_b, (float*)d_out);
    }
}